// Round 5
// baseline (1075.474 us; speedup 1.0000x reference)
//
#include <hip/hip_runtime.h>

#define N_NODES 50000
#define N_EDGES 800000
#define IN_DIM  64
#define EDGE_DIM 16
#define HID     128
#define NLAYERS 3
#define NGRAPH  128
#define EPS     1e-5f

// ==================== init: zero small buffers + CSR counters ====================
__global__ void k_init(int* __restrict__ row_cnt, float* __restrict__ pool,
                       float* __restrict__ gsum, float* __restrict__ gsq) {
    int i = blockIdx.x * blockDim.x + threadIdx.x;
    if (i < N_NODES) row_cnt[i] = 0;
    if (i < NGRAPH * HID) { pool[i] = 0.0f; gsum[i] = 0.0f; gsq[i] = 0.0f; }
}

// ==================== per-graph node counts via binary search (batch sorted) ====================
__global__ __launch_bounds__(NGRAPH) void k_count(const int* __restrict__ batch,
                                                  float* __restrict__ cnt) {
    int g = threadIdx.x;
    int lo = 0, hi = N_NODES;
    while (lo < hi) { int mid = (lo + hi) >> 1; if (batch[mid] < g) lo = mid + 1; else hi = mid; }
    int a = lo;
    lo = 0; hi = N_NODES;
    while (lo < hi) { int mid = (lo + hi) >> 1; if (batch[mid] < g + 1) lo = mid + 1; else hi = mid; }
    cnt[g] = (float)(lo - a);
}

// ==================== CSR build: histogram of dst ====================
__global__ void k_hist(const int* __restrict__ dsts, int* __restrict__ row_cnt) {
    int e = blockIdx.x * blockDim.x + threadIdx.x;
    if (e < N_EDGES) atomicAdd(&row_cnt[dsts[e]], 1);
}

// ==================== scan phase 1 ====================
__global__ __launch_bounds__(256) void k_scan1(const int* __restrict__ row_cnt,
                                               int* __restrict__ partial) {
    __shared__ int s[256];
    int t = threadIdx.x, b = blockIdx.x;
    int i0 = b * 512 + t;
    int v = 0;
    if (i0 < N_NODES) v += row_cnt[i0];
    if (i0 + 256 < N_NODES) v += row_cnt[i0 + 256];
    s[t] = v; __syncthreads();
    for (int off = 128; off > 0; off >>= 1) {
        if (t < off) s[t] += s[t + off];
        __syncthreads();
    }
    if (t == 0) partial[b] = s[0];
}

// ==================== scan phase 2 ====================
#define NCHUNK 98
__global__ __launch_bounds__(128) void k_scan2(int* __restrict__ partial) {
    __shared__ int s[128];
    int t = threadIdx.x;
    int v = (t < NCHUNK) ? partial[t] : 0;
    s[t] = v; __syncthreads();
    for (int off = 1; off < 128; off <<= 1) {
        int x = (t >= off) ? s[t - off] : 0;
        __syncthreads();
        s[t] += x;
        __syncthreads();
    }
    partial[t] = s[t] - v;   // exclusive
}

// ==================== scan phase 3 ====================
__global__ __launch_bounds__(512) void k_scan3(const int* __restrict__ row_cnt,
                                               const int* __restrict__ partial,
                                               int* __restrict__ row_start,
                                               int* __restrict__ row_fill) {
    __shared__ int s[512];
    int t = threadIdx.x, b = blockIdx.x;
    int i = b * 512 + t;
    int v = (i < N_NODES) ? row_cnt[i] : 0;
    s[t] = v; __syncthreads();
    for (int off = 1; off < 512; off <<= 1) {
        int x = (t >= off) ? s[t - off] : 0;
        __syncthreads();
        s[t] += x;
        __syncthreads();
    }
    int excl = s[t] - v + partial[b];
    if (i < N_NODES) { row_start[i] = excl; row_fill[i] = excl; }
}

// ==================== CSR fill: src + permuted edge attrs into CSR order ====================
__global__ void k_fill(const int* __restrict__ srcs, const int* __restrict__ dsts,
                       const float* __restrict__ ea,
                       int* __restrict__ row_fill,
                       int* __restrict__ csr_src, float* __restrict__ csr_ea) {
    int e = blockIdx.x * blockDim.x + threadIdx.x;
    if (e < N_EDGES) {
        int p = atomicAdd(&row_fill[dsts[e]], 1);
        csr_src[p] = srcs[e];
        const float4* s4 = (const float4*)(ea + (size_t)e * EDGE_DIM);
        float4* d4 = (float4*)(csr_ea + (size_t)p * EDGE_DIM);
        d4[0] = s4[0]; d4[1] = s4[1]; d4[2] = s4[2]; d4[3] = s4[3];
    }
}

// ==================== input encoder: 4 nodes/block, both paths, select at end ====================
#define ENC_N 4
__global__ __launch_bounds__(HID) void k_encoder(
    const float* __restrict__ x,
    const float* __restrict__ lw1, const float* __restrict__ lb1,
    const float* __restrict__ lw2, const float* __restrict__ lb2,
    const float* __restrict__ pw1, const float* __restrict__ pb1,
    const float* __restrict__ pw2, const float* __restrict__ pb2,
    float* __restrict__ H) {
    __shared__ float h1l[ENC_N * HID];
    __shared__ float h1p[ENC_N * HID];
    int n0 = blockIdx.x * ENC_N;
    int t = threadIdx.x;
    float accl[ENC_N], accp[ENC_N];
    float bl = lb1[t], bp = pb1[t];
    #pragma unroll
    for (int i = 0; i < ENC_N; ++i) { accl[i] = bl; accp[i] = bp; }
    for (int k4 = 0; k4 < IN_DIM; k4 += 4) {
        float4 a[ENC_N];
        #pragma unroll
        for (int i = 0; i < ENC_N; ++i)
            a[i] = *(const float4*)&x[(n0 + i) * IN_DIM + k4];
        #pragma unroll
        for (int kk = 0; kk < 4; ++kk) {
            float wl = lw1[(k4 + kk) * HID + t];
            float wp = pw1[(k4 + kk) * HID + t];
            #pragma unroll
            for (int i = 0; i < ENC_N; ++i) {
                float c = ((const float*)&a[i])[kk];
                accl[i] = fmaf(c, wl, accl[i]);
                accp[i] = fmaf(c, wp, accp[i]);
            }
        }
    }
    #pragma unroll
    for (int i = 0; i < ENC_N; ++i) {
        h1l[i * HID + t] = fmaxf(accl[i], 0.0f);
        h1p[i * HID + t] = fmaxf(accp[i], 0.0f);
    }
    __syncthreads();
    float bl2 = lb2[t], bp2 = pb2[t];
    #pragma unroll
    for (int i = 0; i < ENC_N; ++i) { accl[i] = bl2; accp[i] = bp2; }
    for (int k4 = 0; k4 < HID; k4 += 4) {
        float4 hl[ENC_N], hp[ENC_N];
        #pragma unroll
        for (int i = 0; i < ENC_N; ++i) {
            hl[i] = *(const float4*)&h1l[i * HID + k4];
            hp[i] = *(const float4*)&h1p[i * HID + k4];
        }
        #pragma unroll
        for (int kk = 0; kk < 4; ++kk) {
            float wl = lw2[(k4 + kk) * HID + t];
            float wp = pw2[(k4 + kk) * HID + t];
            #pragma unroll
            for (int i = 0; i < ENC_N; ++i) {
                accl[i] = fmaf(((const float*)&hl[i])[kk], wl, accl[i]);
                accp[i] = fmaf(((const float*)&hp[i])[kk], wp, accp[i]);
            }
        }
    }
    #pragma unroll
    for (int i = 0; i < ENC_N; ++i) {
        bool prot = x[(n0 + i) * IN_DIM + (IN_DIM - 1)] > 0.5f;
        float v = prot ? accp[i] : accl[i];
        H[(n0 + i) * HID + t] = fmaxf(v, 0.0f);
    }
}

// ==================== edge gather v4: wave/node, contiguous CSR ea, 16 edges in flight ====================
__global__ __launch_bounds__(HID) void k_gather(
    const int* __restrict__ csr_src, const float* __restrict__ csr_ea,
    const int* __restrict__ row_start, const int* __restrict__ row_end,
    const float* __restrict__ ew, const float* __restrict__ eb,
    const float* __restrict__ H, float* __restrict__ A) {
    int wave = threadIdx.x >> 6;          // 0 or 1
    int l    = threadIdx.x & 63;          // lane
    int n = blockIdx.x * 2 + wave;        // node for this wave
    int f = l * 2;                        // feature pair owned by this lane
    float2 ewc[EDGE_DIM];
    #pragma unroll
    for (int k = 0; k < EDGE_DIM; ++k)
        ewc[k] = *(const float2*)&ew[k * HID + f];
    float2 ebv = *(const float2*)&eb[f];
    float2 acc = *(const float2*)&H[n * HID + f];
    int p  = __builtin_amdgcn_readfirstlane(row_start[n]);
    int pe = __builtin_amdgcn_readfirstlane(row_end[n]);
    // 16 edges in flight (src + ea are contiguous wave-uniform -> scalar pipe)
    for (; p + 16 <= pe; p += 16) {
        int s[16];
        #pragma unroll
        for (int j = 0; j < 16; ++j) s[j] = csr_src[p + j];
        float2 h[16];
        #pragma unroll
        for (int j = 0; j < 16; ++j)
            h[j] = *(const float2*)&H[s[j] * HID + f];
        #pragma unroll
        for (int j = 0; j < 16; ++j) {
            const float* q = csr_ea + (size_t)(p + j) * EDGE_DIM;
            float2 lin = ebv;
            #pragma unroll
            for (int k = 0; k < EDGE_DIM; ++k) {
                lin.x = fmaf(q[k], ewc[k].x, lin.x);
                lin.y = fmaf(q[k], ewc[k].y, lin.y);
            }
            acc.x += fmaxf(h[j].x + lin.x, 0.0f);
            acc.y += fmaxf(h[j].y + lin.y, 0.0f);
        }
    }
    for (; p + 4 <= pe; p += 4) {
        int s[4];
        #pragma unroll
        for (int j = 0; j < 4; ++j) s[j] = csr_src[p + j];
        float2 h[4];
        #pragma unroll
        for (int j = 0; j < 4; ++j)
            h[j] = *(const float2*)&H[s[j] * HID + f];
        #pragma unroll
        for (int j = 0; j < 4; ++j) {
            const float* q = csr_ea + (size_t)(p + j) * EDGE_DIM;
            float2 lin = ebv;
            #pragma unroll
            for (int k = 0; k < EDGE_DIM; ++k) {
                lin.x = fmaf(q[k], ewc[k].x, lin.x);
                lin.y = fmaf(q[k], ewc[k].y, lin.y);
            }
            acc.x += fmaxf(h[j].x + lin.x, 0.0f);
            acc.y += fmaxf(h[j].y + lin.y, 0.0f);
        }
    }
    for (; p < pe; ++p) {
        int s0 = csr_src[p];
        float2 h0 = *(const float2*)&H[s0 * HID + f];
        const float* q = csr_ea + (size_t)p * EDGE_DIM;
        float2 lin = ebv;
        #pragma unroll
        for (int k = 0; k < EDGE_DIM; ++k) {
            lin.x = fmaf(q[k], ewc[k].x, lin.x);
            lin.y = fmaf(q[k], ewc[k].y, lin.y);
        }
        acc.x += fmaxf(h0.x + lin.x, 0.0f);
        acc.y += fmaxf(h0.y + lin.y, 0.0f);
    }
    *(float2*)&A[n * HID + f] = acc;
}

// ==================== node MLP v2: 256 thr, 32 nodes, pipelined weight prefetch ====================
#define MLP_N 32
__global__ __launch_bounds__(256) void k_mlp(
    const float* __restrict__ A, const int* __restrict__ batch,
    const float* __restrict__ w1, const float* __restrict__ b1,
    const float* __restrict__ w2, const float* __restrict__ b2,
    float* __restrict__ H, float* __restrict__ gsum, float* __restrict__ gsq) {
    __shared__ float h1s[MLP_N * HID];   // 16 KB
    int n0 = blockIdx.x * MLP_N;
    int t = threadIdx.x;
    int f = t & (HID - 1);
    int half = t >> 7;                   // 0 or 1 -> 16-node subset
    int nb = n0 + half * 16;
    float acc[16];
    float bb = b1[f];
    #pragma unroll
    for (int i = 0; i < 16; ++i) acc[i] = bb;
    float w_cur[4], w_nxt[4];
    #pragma unroll
    for (int kk = 0; kk < 4; ++kk) w_cur[kk] = w1[kk * HID + f];
    for (int k4 = 0; k4 < HID; k4 += 4) {
        if (k4 + 4 < HID) {
            #pragma unroll
            for (int kk = 0; kk < 4; ++kk) w_nxt[kk] = w1[(k4 + 4 + kk) * HID + f];
        }
        float4 a[16];
        #pragma unroll
        for (int i = 0; i < 16; ++i) {
            int ni = nb + i; if (ni >= N_NODES) ni = N_NODES - 1;
            a[i] = *(const float4*)&A[(size_t)ni * HID + k4];
        }
        #pragma unroll
        for (int kk = 0; kk < 4; ++kk)
            #pragma unroll
            for (int i = 0; i < 16; ++i)
                acc[i] = fmaf(((const float*)&a[i])[kk], w_cur[kk], acc[i]);
        #pragma unroll
        for (int kk = 0; kk < 4; ++kk) w_cur[kk] = w_nxt[kk];
    }
    #pragma unroll
    for (int i = 0; i < 16; ++i)
        h1s[(half * 16 + i) * HID + f] = fmaxf(acc[i], 0.0f);
    __syncthreads();
    float bb2 = b2[f];
    #pragma unroll
    for (int i = 0; i < 16; ++i) acc[i] = bb2;
    #pragma unroll
    for (int kk = 0; kk < 4; ++kk) w_cur[kk] = w2[kk * HID + f];
    for (int k4 = 0; k4 < HID; k4 += 4) {
        if (k4 + 4 < HID) {
            #pragma unroll
            for (int kk = 0; kk < 4; ++kk) w_nxt[kk] = w2[(k4 + 4 + kk) * HID + f];
        }
        float4 h[16];
        #pragma unroll
        for (int i = 0; i < 16; ++i)
            h[i] = *(const float4*)&h1s[(half * 16 + i) * HID + k4];
        #pragma unroll
        for (int kk = 0; kk < 4; ++kk)
            #pragma unroll
            for (int i = 0; i < 16; ++i)
                acc[i] = fmaf(((const float*)&h[i])[kk], w_cur[kk], acc[i]);
        #pragma unroll
        for (int kk = 0; kk < 4; ++kk) w_cur[kk] = w_nxt[kk];
    }
    #pragma unroll
    for (int i = 0; i < 16; ++i)
        if (nb + i < N_NODES) H[(size_t)(nb + i) * HID + f] = acc[i];
    int nlast = nb + 15; if (nlast >= N_NODES) nlast = N_NODES - 1;
    int g0 = batch[nb], gN = batch[nlast];
    if (g0 == gN && nb + 15 < N_NODES) {
        float s = 0.0f, q = 0.0f;
        #pragma unroll
        for (int i = 0; i < 16; ++i) { s += acc[i]; q += acc[i] * acc[i]; }
        atomicAdd(&gsum[g0 * HID + f], s);
        atomicAdd(&gsq[g0 * HID + f], q);
    } else {
        #pragma unroll
        for (int i = 0; i < 16; ++i) {
            if (nb + i < N_NODES) {
                int g = batch[nb + i];
                atomicAdd(&gsum[g * HID + f], acc[i]);
                atomicAdd(&gsq[g * HID + f], acc[i] * acc[i]);
            }
        }
    }
}

// ==================== GraphNorm stats -> scale/offset (re-zeros moments) ====================
__global__ __launch_bounds__(HID) void k_stats(
    float* __restrict__ gsum, float* __restrict__ gsq,
    const float* __restrict__ cnt,
    const float* __restrict__ gw, const float* __restrict__ gb,
    const float* __restrict__ gms,
    float* __restrict__ sc, float* __restrict__ of) {
    int g = blockIdx.x;
    int t = threadIdx.x;
    float c = fmaxf(cnt[g], 1.0f);
    float mean = gsum[g * HID + t] / c;
    float msq  = gsq[g * HID + t] / c;
    float ms = gms[t];
    float var = msq - mean * mean * ms * (2.0f - ms);
    var = fmaxf(var, 0.0f);
    float istd = rsqrtf(var + EPS);
    float s = gw[t] * istd;
    sc[g * HID + t] = s;
    of[g * HID + t] = gb[t] - s * mean * ms;
    gsum[g * HID + t] = 0.0f;
    gsq[g * HID + t]  = 0.0f;
}

// ==================== normalize + relu (+ pooled global_add on last layer) ====================
#define NORM_N 8
__global__ __launch_bounds__(HID) void k_norm(
    float* __restrict__ H, const int* __restrict__ batch,
    const float* __restrict__ sc, const float* __restrict__ of,
    float* __restrict__ pool, int accumulate) {
    int n0 = blockIdx.x * NORM_N;
    int t = threadIdx.x;
    int g0 = batch[n0], gN = batch[n0 + NORM_N - 1];
    if (g0 == gN) {
        float ssc = sc[g0 * HID + t], sof = of[g0 * HID + t];
        float ps = 0.0f;
        #pragma unroll
        for (int i = 0; i < NORM_N; ++i) {
            float v = fmaxf(H[(n0 + i) * HID + t] * ssc + sof, 0.0f);
            H[(n0 + i) * HID + t] = v;
            ps += v;
        }
        if (accumulate) atomicAdd(&pool[g0 * HID + t], ps);
    } else {
        #pragma unroll
        for (int i = 0; i < NORM_N; ++i) {
            int g = batch[n0 + i];
            float v = fmaxf(H[(n0 + i) * HID + t] * sc[g * HID + t] + of[g * HID + t], 0.0f);
            H[(n0 + i) * HID + t] = v;
            if (accumulate) atomicAdd(&pool[g * HID + t], v);
        }
    }
}

// ==================== output head ====================
__global__ __launch_bounds__(HID) void k_head(
    const float* __restrict__ pool,
    const float* __restrict__ fw1, const float* __restrict__ fb1,
    const float* __restrict__ fw2, const float* __restrict__ fb2,
    float* __restrict__ out) {
    __shared__ float ps[HID];
    __shared__ float red[2];
    int g = blockIdx.x;
    int t = threadIdx.x;
    ps[t] = pool[g * HID + t];
    __syncthreads();
    float acc = fb1[t];
    #pragma unroll 4
    for (int k = 0; k < HID; ++k) acc = fmaf(ps[k], fw1[k * HID + t], acc);
    float p = fmaxf(acc, 0.0f) * fw2[t];
    #pragma unroll
    for (int off = 32; off > 0; off >>= 1) p += __shfl_down(p, off, 64);
    if ((t & 63) == 0) red[t >> 6] = p;
    __syncthreads();
    if (t == 0) out[g] = red[0] + red[1] + fb2[0];
}

extern "C" void kernel_launch(void* const* d_in, const int* in_sizes, int n_in,
                              void* d_out, int out_size, void* d_ws, size_t ws_size,
                              hipStream_t stream) {
    const float* x     = (const float*)d_in[0];
    const int*   ei    = (const int*)d_in[1];
    const float* ea    = (const float*)d_in[2];
    const int*   batch = (const int*)d_in[3];
    const float* lw1 = (const float*)d_in[4];
    const float* lb1 = (const float*)d_in[5];
    const float* lw2 = (const float*)d_in[6];
    const float* lb2 = (const float*)d_in[7];
    const float* pw1 = (const float*)d_in[8];
    const float* pb1 = (const float*)d_in[9];
    const float* pw2 = (const float*)d_in[10];
    const float* pb2 = (const float*)d_in[11];
    const float* ew  = (const float*)d_in[12];
    const float* eb  = (const float*)d_in[13];
    const float* nw1 = (const float*)d_in[14];
    const float* nb1 = (const float*)d_in[15];
    const float* nw2 = (const float*)d_in[16];
    const float* nb2 = (const float*)d_in[17];
    const float* gw  = (const float*)d_in[18];
    const float* gb  = (const float*)d_in[19];
    const float* gms = (const float*)d_in[20];
    const float* fw1 = (const float*)d_in[21];
    const float* fb1 = (const float*)d_in[22];
    const float* fw2 = (const float*)d_in[23];
    const float* fb2 = (const float*)d_in[24];
    float* out = (float*)d_out;

    float* ws   = (float*)d_ws;
    float* H    = ws;                          // 6,400,000 f
    float* A    = H    + (size_t)N_NODES * HID;// 6,400,000 f
    float* gsum = A    + (size_t)N_NODES * HID;
    float* gsq  = gsum + NGRAPH * HID;
    float* sc   = gsq  + NGRAPH * HID;
    float* of   = sc   + NGRAPH * HID;
    float* pool = of   + NGRAPH * HID;
    float* cnt  = pool + NGRAPH * HID;         // 128 f
    int* row_cnt   = (int*)(cnt + NGRAPH);     // 50000
    int* row_start = row_cnt + N_NODES;        // 50000
    int* row_fill  = row_start + N_NODES;      // 50000
    int* partial   = row_fill + N_NODES;       // 128
    int* csr_src   = partial + 128;            // 800000
    float* csr_ea  = (float*)(csr_src + N_EDGES); // 12,800,000 f (51.2 MB)

    const int* srcs = ei;
    const int* dsts = ei + N_EDGES;

    // ---- init + CSR build ----
    k_init<<<(N_NODES + 255) / 256, 256, 0, stream>>>(row_cnt, pool, gsum, gsq);
    k_count<<<1, NGRAPH, 0, stream>>>(batch, cnt);
    k_hist<<<(N_EDGES + 255) / 256, 256, 0, stream>>>(dsts, row_cnt);
    k_scan1<<<NCHUNK, 256, 0, stream>>>(row_cnt, partial);
    k_scan2<<<1, 128, 0, stream>>>(partial);
    k_scan3<<<NCHUNK, 512, 0, stream>>>(row_cnt, partial, row_start, row_fill);
    k_fill<<<(N_EDGES + 255) / 256, 256, 0, stream>>>(srcs, dsts, ea, row_fill,
                                                      csr_src, csr_ea);

    // ---- encoder ----
    k_encoder<<<N_NODES / ENC_N, HID, 0, stream>>>(x, lw1, lb1, lw2, lb2,
                                                   pw1, pb1, pw2, pb2, H);

    // ---- layers ----
    for (int l = 0; l < NLAYERS; ++l) {
        k_gather<<<N_NODES / 2, HID, 0, stream>>>(
            csr_src, csr_ea, row_start, row_fill,
            ew + l * EDGE_DIM * HID, eb + l * HID, H, A);
        k_mlp<<<(N_NODES + MLP_N - 1) / MLP_N, 256, 0, stream>>>(
            A, batch, nw1 + l * HID * HID, nb1 + l * HID,
            nw2 + l * HID * HID, nb2 + l * HID, H, gsum, gsq);
        k_stats<<<NGRAPH, HID, 0, stream>>>(gsum, gsq, cnt,
                                            gw + l * HID, gb + l * HID, gms + l * HID,
                                            sc, of);
        k_norm<<<N_NODES / NORM_N, HID, 0, stream>>>(
            H, batch, sc, of, pool, (l == NLAYERS - 1) ? 1 : 0);
    }
    k_head<<<NGRAPH, HID, 0, stream>>>(pool, fw1, fb1, fw2, fb2, out);
}

// Round 6
// 779.471 us; speedup vs baseline: 1.3797x; 1.3797x over previous
//
#include <hip/hip_runtime.h>

#define N_NODES 50000
#define N_EDGES 800000
#define IN_DIM  64
#define EDGE_DIM 16
#define HID     128
#define NLAYERS 3
#define NGRAPH  128
#define EPS     1e-5f

typedef __attribute__((ext_vector_type(8))) short bf8_t;
typedef __attribute__((ext_vector_type(4))) float f32x4;

__device__ __forceinline__ unsigned short f2bf(float x) {
    unsigned u = __float_as_uint(x);
    unsigned r = u + 0x7fffu + ((u >> 16) & 1u);   // round-to-nearest-even
    return (unsigned short)(r >> 16);
}

// ==================== init: zero small buffers + CSR counters ====================
__global__ void k_init(int* __restrict__ row_cnt, float* __restrict__ pool,
                       float* __restrict__ gsum, float* __restrict__ gsq) {
    int i = blockIdx.x * blockDim.x + threadIdx.x;
    if (i < N_NODES) row_cnt[i] = 0;
    if (i < NGRAPH * HID) { pool[i] = 0.0f; gsum[i] = 0.0f; gsq[i] = 0.0f; }
}

// ==================== per-graph node counts via binary search (batch sorted) ====================
__global__ __launch_bounds__(NGRAPH) void k_count(const int* __restrict__ batch,
                                                  float* __restrict__ cnt) {
    int g = threadIdx.x;
    int lo = 0, hi = N_NODES;
    while (lo < hi) { int mid = (lo + hi) >> 1; if (batch[mid] < g) lo = mid + 1; else hi = mid; }
    int a = lo;
    lo = 0; hi = N_NODES;
    while (lo < hi) { int mid = (lo + hi) >> 1; if (batch[mid] < g + 1) lo = mid + 1; else hi = mid; }
    cnt[g] = (float)(lo - a);
}

// ==================== weight transpose + bf16 convert: wt[l][which][n][k] ====================
__global__ void k_wconv(const float* __restrict__ nw1, const float* __restrict__ nw2,
                        unsigned short* __restrict__ wt) {
    int idx = blockIdx.x * 256 + threadIdx.x;
    if (idx >= NLAYERS * 2 * HID * HID) return;
    int k = idx & 127;
    int n = (idx >> 7) & 127;
    int which = (idx >> 14) & 1;
    int l = idx >> 15;
    const float* w = (which == 0 ? nw1 : nw2) + l * HID * HID;
    wt[idx] = f2bf(w[k * HID + n]);
}

// ==================== CSR build: histogram of dst ====================
__global__ void k_hist(const int* __restrict__ dsts, int* __restrict__ row_cnt) {
    int e = blockIdx.x * blockDim.x + threadIdx.x;
    if (e < N_EDGES) atomicAdd(&row_cnt[dsts[e]], 1);
}

// ==================== scan phase 1 ====================
__global__ __launch_bounds__(256) void k_scan1(const int* __restrict__ row_cnt,
                                               int* __restrict__ partial) {
    __shared__ int s[256];
    int t = threadIdx.x, b = blockIdx.x;
    int i0 = b * 512 + t;
    int v = 0;
    if (i0 < N_NODES) v += row_cnt[i0];
    if (i0 + 256 < N_NODES) v += row_cnt[i0 + 256];
    s[t] = v; __syncthreads();
    for (int off = 128; off > 0; off >>= 1) {
        if (t < off) s[t] += s[t + off];
        __syncthreads();
    }
    if (t == 0) partial[b] = s[0];
}

// ==================== scan phase 2 ====================
#define NCHUNK 98
__global__ __launch_bounds__(128) void k_scan2(int* __restrict__ partial) {
    __shared__ int s[128];
    int t = threadIdx.x;
    int v = (t < NCHUNK) ? partial[t] : 0;
    s[t] = v; __syncthreads();
    for (int off = 1; off < 128; off <<= 1) {
        int x = (t >= off) ? s[t - off] : 0;
        __syncthreads();
        s[t] += x;
        __syncthreads();
    }
    partial[t] = s[t] - v;   // exclusive
}

// ==================== scan phase 3 ====================
__global__ __launch_bounds__(512) void k_scan3(const int* __restrict__ row_cnt,
                                               const int* __restrict__ partial,
                                               int* __restrict__ row_start,
                                               int* __restrict__ row_fill) {
    __shared__ int s[512];
    int t = threadIdx.x, b = blockIdx.x;
    int i = b * 512 + t;
    int v = (i < N_NODES) ? row_cnt[i] : 0;
    s[t] = v; __syncthreads();
    for (int off = 1; off < 512; off <<= 1) {
        int x = (t >= off) ? s[t - off] : 0;
        __syncthreads();
        s[t] += x;
        __syncthreads();
    }
    int excl = s[t] - v + partial[b];
    if (i < N_NODES) { row_start[i] = excl; row_fill[i] = excl; }
}

// ==================== CSR fill: src + permuted edge attrs into CSR order ====================
__global__ void k_fill(const int* __restrict__ srcs, const int* __restrict__ dsts,
                       const float* __restrict__ ea,
                       int* __restrict__ row_fill,
                       int* __restrict__ csr_src, float* __restrict__ csr_ea) {
    int e = blockIdx.x * blockDim.x + threadIdx.x;
    if (e < N_EDGES) {
        int p = atomicAdd(&row_fill[dsts[e]], 1);
        csr_src[p] = srcs[e];
        const float4* s4 = (const float4*)(ea + (size_t)e * EDGE_DIM);
        float4* d4 = (float4*)(csr_ea + (size_t)p * EDGE_DIM);
        d4[0] = s4[0]; d4[1] = s4[1]; d4[2] = s4[2]; d4[3] = s4[3];
    }
}

// ==================== input encoder: 4 nodes/block, both paths, select at end ====================
#define ENC_N 4
__global__ __launch_bounds__(HID) void k_encoder(
    const float* __restrict__ x,
    const float* __restrict__ lw1, const float* __restrict__ lb1,
    const float* __restrict__ lw2, const float* __restrict__ lb2,
    const float* __restrict__ pw1, const float* __restrict__ pb1,
    const float* __restrict__ pw2, const float* __restrict__ pb2,
    float* __restrict__ H) {
    __shared__ float h1l[ENC_N * HID];
    __shared__ float h1p[ENC_N * HID];
    int n0 = blockIdx.x * ENC_N;
    int t = threadIdx.x;
    float accl[ENC_N], accp[ENC_N];
    float bl = lb1[t], bp = pb1[t];
    #pragma unroll
    for (int i = 0; i < ENC_N; ++i) { accl[i] = bl; accp[i] = bp; }
    for (int k4 = 0; k4 < IN_DIM; k4 += 4) {
        float4 a[ENC_N];
        #pragma unroll
        for (int i = 0; i < ENC_N; ++i)
            a[i] = *(const float4*)&x[(n0 + i) * IN_DIM + k4];
        #pragma unroll
        for (int kk = 0; kk < 4; ++kk) {
            float wl = lw1[(k4 + kk) * HID + t];
            float wp = pw1[(k4 + kk) * HID + t];
            #pragma unroll
            for (int i = 0; i < ENC_N; ++i) {
                float c = ((const float*)&a[i])[kk];
                accl[i] = fmaf(c, wl, accl[i]);
                accp[i] = fmaf(c, wp, accp[i]);
            }
        }
    }
    #pragma unroll
    for (int i = 0; i < ENC_N; ++i) {
        h1l[i * HID + t] = fmaxf(accl[i], 0.0f);
        h1p[i * HID + t] = fmaxf(accp[i], 0.0f);
    }
    __syncthreads();
    float bl2 = lb2[t], bp2 = pb2[t];
    #pragma unroll
    for (int i = 0; i < ENC_N; ++i) { accl[i] = bl2; accp[i] = bp2; }
    for (int k4 = 0; k4 < HID; k4 += 4) {
        float4 hl[ENC_N], hp[ENC_N];
        #pragma unroll
        for (int i = 0; i < ENC_N; ++i) {
            hl[i] = *(const float4*)&h1l[i * HID + k4];
            hp[i] = *(const float4*)&h1p[i * HID + k4];
        }
        #pragma unroll
        for (int kk = 0; kk < 4; ++kk) {
            float wl = lw2[(k4 + kk) * HID + t];
            float wp = pw2[(k4 + kk) * HID + t];
            #pragma unroll
            for (int i = 0; i < ENC_N; ++i) {
                accl[i] = fmaf(((const float*)&hl[i])[kk], wl, accl[i]);
                accp[i] = fmaf(((const float*)&hp[i])[kk], wp, accp[i]);
            }
        }
    }
    #pragma unroll
    for (int i = 0; i < ENC_N; ++i) {
        bool prot = x[(n0 + i) * IN_DIM + (IN_DIM - 1)] > 0.5f;
        float v = prot ? accp[i] : accl[i];
        H[(n0 + i) * HID + t] = fmaxf(v, 0.0f);
    }
}

// ==================== edge gather v4: wave/node, contiguous CSR ea, 16 edges in flight ====================
__global__ __launch_bounds__(HID) void k_gather(
    const int* __restrict__ csr_src, const float* __restrict__ csr_ea,
    const int* __restrict__ row_start, const int* __restrict__ row_end,
    const float* __restrict__ ew, const float* __restrict__ eb,
    const float* __restrict__ H, float* __restrict__ A) {
    int wave = threadIdx.x >> 6;
    int l    = threadIdx.x & 63;
    int n = blockIdx.x * 2 + wave;
    int f = l * 2;
    float2 ewc[EDGE_DIM];
    #pragma unroll
    for (int k = 0; k < EDGE_DIM; ++k)
        ewc[k] = *(const float2*)&ew[k * HID + f];
    float2 ebv = *(const float2*)&eb[f];
    float2 acc = *(const float2*)&H[n * HID + f];
    int p  = __builtin_amdgcn_readfirstlane(row_start[n]);
    int pe = __builtin_amdgcn_readfirstlane(row_end[n]);
    for (; p + 16 <= pe; p += 16) {
        int s[16];
        #pragma unroll
        for (int j = 0; j < 16; ++j) s[j] = csr_src[p + j];
        float2 h[16];
        #pragma unroll
        for (int j = 0; j < 16; ++j)
            h[j] = *(const float2*)&H[s[j] * HID + f];
        #pragma unroll
        for (int j = 0; j < 16; ++j) {
            const float* q = csr_ea + (size_t)(p + j) * EDGE_DIM;
            float2 lin = ebv;
            #pragma unroll
            for (int k = 0; k < EDGE_DIM; ++k) {
                lin.x = fmaf(q[k], ewc[k].x, lin.x);
                lin.y = fmaf(q[k], ewc[k].y, lin.y);
            }
            acc.x += fmaxf(h[j].x + lin.x, 0.0f);
            acc.y += fmaxf(h[j].y + lin.y, 0.0f);
        }
    }
    for (; p + 4 <= pe; p += 4) {
        int s[4];
        #pragma unroll
        for (int j = 0; j < 4; ++j) s[j] = csr_src[p + j];
        float2 h[4];
        #pragma unroll
        for (int j = 0; j < 4; ++j)
            h[j] = *(const float2*)&H[s[j] * HID + f];
        #pragma unroll
        for (int j = 0; j < 4; ++j) {
            const float* q = csr_ea + (size_t)(p + j) * EDGE_DIM;
            float2 lin = ebv;
            #pragma unroll
            for (int k = 0; k < EDGE_DIM; ++k) {
                lin.x = fmaf(q[k], ewc[k].x, lin.x);
                lin.y = fmaf(q[k], ewc[k].y, lin.y);
            }
            acc.x += fmaxf(h[j].x + lin.x, 0.0f);
            acc.y += fmaxf(h[j].y + lin.y, 0.0f);
        }
    }
    for (; p < pe; ++p) {
        int s0 = csr_src[p];
        float2 h0 = *(const float2*)&H[s0 * HID + f];
        const float* q = csr_ea + (size_t)p * EDGE_DIM;
        float2 lin = ebv;
        #pragma unroll
        for (int k = 0; k < EDGE_DIM; ++k) {
            lin.x = fmaf(q[k], ewc[k].x, lin.x);
            lin.y = fmaf(q[k], ewc[k].y, lin.y);
        }
        acc.x += fmaxf(h0.x + lin.x, 0.0f);
        acc.y += fmaxf(h0.y + lin.y, 0.0f);
    }
    *(float2*)&A[n * HID + f] = acc;
}

// ==================== node MLP via MFMA: 4 waves/block, 16 nodes/wave ====================
// GEMM1: h1 = relu(A @ W1 + b1); GEMM2: H = h1 @ W2 + b2, fused moment atomics.
// wt: bf16 transposed weights [l][which][n][k]. LDS round-trip converts C-layout -> A-layout.
#define HS 136   // LDS row stride in shorts (128 + 8 pad: keeps 16B alignment, <=2-way banks)
#define MLP_NODES_PER_BLOCK 64
__global__ __launch_bounds__(256) void k_mlp_mfma(
    const float* __restrict__ A, const int* __restrict__ batch,
    const unsigned short* __restrict__ wt1, const unsigned short* __restrict__ wt2,
    const float* __restrict__ b1, const float* __restrict__ b2,
    float* __restrict__ H, float* __restrict__ gsum, float* __restrict__ gsq) {
    __shared__ short h1s[4 * 16 * HS];   // 17408 B
    int w = threadIdx.x >> 6;            // wave 0..3
    int lane = threadIdx.x & 63;
    int m = lane & 15;                   // row-operand index / output col
    int quad = lane >> 4;                // 0..3
    int nb = blockIdx.x * MLP_NODES_PER_BLOCK + w * 16;
    short* hw = h1s + w * 16 * HS;

    // ---- GEMM1: acc1 = A[nb..nb+15][0..127] @ W1 + b1 ----
    int nclamp = nb + m; if (nclamp >= N_NODES) nclamp = N_NODES - 1;
    const float* Ap = A + (size_t)nclamp * HID;
    f32x4 acc1[8];
    #pragma unroll
    for (int t = 0; t < 8; ++t) {
        float bv = b1[t * 16 + m];
        acc1[t] = (f32x4){bv, bv, bv, bv};
    }
    #pragma unroll
    for (int s_ = 0; s_ < 4; ++s_) {
        int k0 = s_ * 32 + quad * 8;
        float4 a0 = *(const float4*)(Ap + k0);
        float4 a1 = *(const float4*)(Ap + k0 + 4);
        bf8_t af;
        af[0] = (short)f2bf(a0.x); af[1] = (short)f2bf(a0.y);
        af[2] = (short)f2bf(a0.z); af[3] = (short)f2bf(a0.w);
        af[4] = (short)f2bf(a1.x); af[5] = (short)f2bf(a1.y);
        af[6] = (short)f2bf(a1.z); af[7] = (short)f2bf(a1.w);
        #pragma unroll
        for (int t = 0; t < 8; ++t) {
            bf8_t bf = *(const bf8_t*)(wt1 + (t * 16 + m) * HID + k0);
            acc1[t] = __builtin_amdgcn_mfma_f32_16x16x32_bf16(af, bf, acc1[t], 0, 0, 0);
        }
    }
    // ---- relu -> bf16 -> LDS (C-layout write) ----
    #pragma unroll
    for (int t = 0; t < 8; ++t)
        #pragma unroll
        for (int r = 0; r < 4; ++r) {
            float v = fmaxf(acc1[t][r], 0.0f);
            hw[(quad * 4 + r) * HS + t * 16 + m] = (short)f2bf(v);
        }
    __syncthreads();
    // ---- GEMM2: acc2 = h1 @ W2 + b2 (A-layout read from LDS) ----
    f32x4 acc2[8];
    #pragma unroll
    for (int t = 0; t < 8; ++t) {
        float bv = b2[t * 16 + m];
        acc2[t] = (f32x4){bv, bv, bv, bv};
    }
    #pragma unroll
    for (int s_ = 0; s_ < 4; ++s_) {
        int k0 = s_ * 32 + quad * 8;
        bf8_t af = *(const bf8_t*)(hw + m * HS + k0);
        #pragma unroll
        for (int t = 0; t < 8; ++t) {
            bf8_t bf = *(const bf8_t*)(wt2 + (t * 16 + m) * HID + k0);
            acc2[t] = __builtin_amdgcn_mfma_f32_16x16x32_bf16(af, bf, acc2[t], 0, 0, 0);
        }
    }
    // ---- store H + moment atomics ----
    #pragma unroll
    for (int t = 0; t < 8; ++t)
        #pragma unroll
        for (int r = 0; r < 4; ++r) {
            int node = nb + quad * 4 + r;
            if (node < N_NODES) H[(size_t)node * HID + t * 16 + m] = acc2[t][r];
        }
    int blast = nb + 15 < N_NODES ? batch[nb + 15] : -1;
    int g0 = batch[nb < N_NODES ? nb : N_NODES - 1];
    if (nb + 15 < N_NODES && g0 == blast) {
        // clean: all 16 nodes one graph -> shuffle-reduce across quads, 1 atomic/feature
        #pragma unroll
        for (int t = 0; t < 8; ++t) {
            float s = 0.0f, q = 0.0f;
            #pragma unroll
            for (int r = 0; r < 4; ++r) { float v = acc2[t][r]; s += v; q += v * v; }
            s += __shfl_xor(s, 16); q += __shfl_xor(q, 16);
            s += __shfl_xor(s, 32); q += __shfl_xor(q, 32);
            if (quad == 0) {
                atomicAdd(&gsum[g0 * HID + t * 16 + m], s);
                atomicAdd(&gsq[g0 * HID + t * 16 + m], q);
            }
        }
    } else {
        #pragma unroll
        for (int t = 0; t < 8; ++t)
            #pragma unroll
            for (int r = 0; r < 4; ++r) {
                int node = nb + quad * 4 + r;
                if (node < N_NODES) {
                    int g = batch[node];
                    float v = acc2[t][r];
                    atomicAdd(&gsum[g * HID + t * 16 + m], v);
                    atomicAdd(&gsq[g * HID + t * 16 + m], v * v);
                }
            }
    }
}

// ==================== GraphNorm stats -> scale/offset (re-zeros moments) ====================
__global__ __launch_bounds__(HID) void k_stats(
    float* __restrict__ gsum, float* __restrict__ gsq,
    const float* __restrict__ cnt,
    const float* __restrict__ gw, const float* __restrict__ gb,
    const float* __restrict__ gms,
    float* __restrict__ sc, float* __restrict__ of) {
    int g = blockIdx.x;
    int t = threadIdx.x;
    float c = fmaxf(cnt[g], 1.0f);
    float mean = gsum[g * HID + t] / c;
    float msq  = gsq[g * HID + t] / c;
    float ms = gms[t];
    float var = msq - mean * mean * ms * (2.0f - ms);
    var = fmaxf(var, 0.0f);
    float istd = rsqrtf(var + EPS);
    float s = gw[t] * istd;
    sc[g * HID + t] = s;
    of[g * HID + t] = gb[t] - s * mean * ms;
    gsum[g * HID + t] = 0.0f;
    gsq[g * HID + t]  = 0.0f;
}

// ==================== normalize + relu (+ pooled global_add on last layer) ====================
#define NORM_N 8
__global__ __launch_bounds__(HID) void k_norm(
    float* __restrict__ H, const int* __restrict__ batch,
    const float* __restrict__ sc, const float* __restrict__ of,
    float* __restrict__ pool, int accumulate) {
    int n0 = blockIdx.x * NORM_N;
    int t = threadIdx.x;
    int g0 = batch[n0], gN = batch[n0 + NORM_N - 1];
    if (g0 == gN) {
        float ssc = sc[g0 * HID + t], sof = of[g0 * HID + t];
        float ps = 0.0f;
        #pragma unroll
        for (int i = 0; i < NORM_N; ++i) {
            float v = fmaxf(H[(n0 + i) * HID + t] * ssc + sof, 0.0f);
            H[(n0 + i) * HID + t] = v;
            ps += v;
        }
        if (accumulate) atomicAdd(&pool[g0 * HID + t], ps);
    } else {
        #pragma unroll
        for (int i = 0; i < NORM_N; ++i) {
            int g = batch[n0 + i];
            float v = fmaxf(H[(n0 + i) * HID + t] * sc[g * HID + t] + of[g * HID + t], 0.0f);
            H[(n0 + i) * HID + t] = v;
            if (accumulate) atomicAdd(&pool[g * HID + t], v);
        }
    }
}

// ==================== output head ====================
__global__ __launch_bounds__(HID) void k_head(
    const float* __restrict__ pool,
    const float* __restrict__ fw1, const float* __restrict__ fb1,
    const float* __restrict__ fw2, const float* __restrict__ fb2,
    float* __restrict__ out) {
    __shared__ float ps[HID];
    __shared__ float red[2];
    int g = blockIdx.x;
    int t = threadIdx.x;
    ps[t] = pool[g * HID + t];
    __syncthreads();
    float acc = fb1[t];
    #pragma unroll 4
    for (int k = 0; k < HID; ++k) acc = fmaf(ps[k], fw1[k * HID + t], acc);
    float p = fmaxf(acc, 0.0f) * fw2[t];
    #pragma unroll
    for (int off = 32; off > 0; off >>= 1) p += __shfl_down(p, off, 64);
    if ((t & 63) == 0) red[t >> 6] = p;
    __syncthreads();
    if (t == 0) out[g] = red[0] + red[1] + fb2[0];
}

extern "C" void kernel_launch(void* const* d_in, const int* in_sizes, int n_in,
                              void* d_out, int out_size, void* d_ws, size_t ws_size,
                              hipStream_t stream) {
    const float* x     = (const float*)d_in[0];
    const int*   ei    = (const int*)d_in[1];
    const float* ea    = (const float*)d_in[2];
    const int*   batch = (const int*)d_in[3];
    const float* lw1 = (const float*)d_in[4];
    const float* lb1 = (const float*)d_in[5];
    const float* lw2 = (const float*)d_in[6];
    const float* lb2 = (const float*)d_in[7];
    const float* pw1 = (const float*)d_in[8];
    const float* pb1 = (const float*)d_in[9];
    const float* pw2 = (const float*)d_in[10];
    const float* pb2 = (const float*)d_in[11];
    const float* ew  = (const float*)d_in[12];
    const float* eb  = (const float*)d_in[13];
    const float* nw1 = (const float*)d_in[14];
    const float* nb1 = (const float*)d_in[15];
    const float* nw2 = (const float*)d_in[16];
    const float* nb2 = (const float*)d_in[17];
    const float* gw  = (const float*)d_in[18];
    const float* gb  = (const float*)d_in[19];
    const float* gms = (const float*)d_in[20];
    const float* fw1 = (const float*)d_in[21];
    const float* fb1 = (const float*)d_in[22];
    const float* fw2 = (const float*)d_in[23];
    const float* fb2 = (const float*)d_in[24];
    float* out = (float*)d_out;

    float* ws   = (float*)d_ws;
    float* H    = ws;                          // 6,400,000 f
    float* A    = H    + (size_t)N_NODES * HID;// 6,400,000 f
    float* gsum = A    + (size_t)N_NODES * HID;
    float* gsq  = gsum + NGRAPH * HID;
    float* sc   = gsq  + NGRAPH * HID;
    float* of   = sc   + NGRAPH * HID;
    float* pool = of   + NGRAPH * HID;
    float* cnt  = pool + NGRAPH * HID;         // 128 f
    int* row_cnt   = (int*)(cnt + NGRAPH);     // 50000
    int* row_start = row_cnt + N_NODES;        // 50000
    int* row_fill  = row_start + N_NODES;      // 50000
    int* partial   = row_fill + N_NODES;       // 128
    int* csr_src   = partial + 128;            // 800000
    float* csr_ea  = (float*)(csr_src + N_EDGES);          // 12,800,000 f
    unsigned short* wt = (unsigned short*)(csr_ea + (size_t)N_EDGES * EDGE_DIM); // 98304 bf16

    const int* srcs = ei;
    const int* dsts = ei + N_EDGES;

    // ---- init + CSR build + weight conversion ----
    k_init<<<(N_NODES + 255) / 256, 256, 0, stream>>>(row_cnt, pool, gsum, gsq);
    k_count<<<1, NGRAPH, 0, stream>>>(batch, cnt);
    k_wconv<<<(NLAYERS * 2 * HID * HID + 255) / 256, 256, 0, stream>>>(nw1, nw2, wt);
    k_hist<<<(N_EDGES + 255) / 256, 256, 0, stream>>>(dsts, row_cnt);
    k_scan1<<<NCHUNK, 256, 0, stream>>>(row_cnt, partial);
    k_scan2<<<1, 128, 0, stream>>>(partial);
    k_scan3<<<NCHUNK, 512, 0, stream>>>(row_cnt, partial, row_start, row_fill);
    k_fill<<<(N_EDGES + 255) / 256, 256, 0, stream>>>(srcs, dsts, ea, row_fill,
                                                      csr_src, csr_ea);

    // ---- encoder ----
    k_encoder<<<N_NODES / ENC_N, HID, 0, stream>>>(x, lw1, lb1, lw2, lb2,
                                                   pw1, pb1, pw2, pb2, H);

    // ---- layers ----
    int mlp_blocks = (N_NODES + MLP_NODES_PER_BLOCK - 1) / MLP_NODES_PER_BLOCK;
    for (int l = 0; l < NLAYERS; ++l) {
        k_gather<<<N_NODES / 2, HID, 0, stream>>>(
            csr_src, csr_ea, row_start, row_fill,
            ew + l * EDGE_DIM * HID, eb + l * HID, H, A);
        k_mlp_mfma<<<mlp_blocks, 256, 0, stream>>>(
            A, batch,
            wt + (size_t)l * 2 * HID * HID,
            wt + (size_t)l * 2 * HID * HID + HID * HID,
            nb1 + l * HID, nb2 + l * HID, H, gsum, gsq);
        k_stats<<<NGRAPH, HID, 0, stream>>>(gsum, gsq, cnt,
                                            gw + l * HID, gb + l * HID, gms + l * HID,
                                            sc, of);
        k_norm<<<N_NODES / NORM_N, HID, 0, stream>>>(
            H, batch, sc, of, pool, (l == NLAYERS - 1) ? 1 : 0);
    }
    k_head<<<NGRAPH, HID, 0, stream>>>(pool, fw1, fb1, fw2, fb2, out);
}

// Round 7
// 735.331 us; speedup vs baseline: 1.4626x; 1.0600x over previous
//
#include <hip/hip_runtime.h>

#define N_NODES 50000
#define N_EDGES 800000
#define IN_DIM  64
#define EDGE_DIM 16
#define HID     128
#define NLAYERS 3
#define NGRAPH  128
#define EPS     1e-5f

typedef __attribute__((ext_vector_type(8))) short bf8_t;
typedef __attribute__((ext_vector_type(4))) float f32x4;

__device__ __forceinline__ unsigned short f2bf(float x) {
    unsigned u = __float_as_uint(x);
    unsigned r = u + 0x7fffu + ((u >> 16) & 1u);   // round-to-nearest-even
    return (unsigned short)(r >> 16);
}

// ==================== init ====================
__global__ void k_init(int* __restrict__ row_cnt, float* __restrict__ pool,
                       float* __restrict__ gsum, float* __restrict__ gsq) {
    int i = blockIdx.x * blockDim.x + threadIdx.x;
    if (i < N_NODES) row_cnt[i] = 0;
    if (i < NGRAPH * HID) { pool[i] = 0.0f; gsum[i] = 0.0f; gsq[i] = 0.0f; }
}

// ==================== per-graph node counts via binary search ====================
__global__ __launch_bounds__(NGRAPH) void k_count(const int* __restrict__ batch,
                                                  float* __restrict__ cnt) {
    int g = threadIdx.x;
    int lo = 0, hi = N_NODES;
    while (lo < hi) { int mid = (lo + hi) >> 1; if (batch[mid] < g) lo = mid + 1; else hi = mid; }
    int a = lo;
    lo = 0; hi = N_NODES;
    while (lo < hi) { int mid = (lo + hi) >> 1; if (batch[mid] < g + 1) lo = mid + 1; else hi = mid; }
    cnt[g] = (float)(lo - a);
}

// ==================== nn weights -> bf16 transposed [l][which][n][k] ====================
__global__ void k_wconv(const float* __restrict__ nw1, const float* __restrict__ nw2,
                        unsigned short* __restrict__ wt) {
    int idx = blockIdx.x * 256 + threadIdx.x;
    if (idx >= NLAYERS * 2 * HID * HID) return;
    int k = idx & 127;
    int n = (idx >> 7) & 127;
    int which = (idx >> 14) & 1;
    int l = idx >> 15;
    const float* w = (which == 0 ? nw1 : nw2) + l * HID * HID;
    wt[idx] = f2bf(w[k * HID + n]);
}

// ==================== encoder weights -> bf16 transposed ====================
// layout: lw1t[128][64] @0, pw1t @8192, lw2t[128][128] @16384, pw2t @32768
__global__ void k_wconv_enc(const float* __restrict__ lw1, const float* __restrict__ pw1,
                            const float* __restrict__ lw2, const float* __restrict__ pw2,
                            unsigned short* __restrict__ we) {
    int idx = blockIdx.x * 256 + threadIdx.x;
    if (idx >= 49152) return;
    float v;
    if (idx < 8192)       { int n = idx >> 6, k = idx & 63;            v = lw1[k * HID + n]; }
    else if (idx < 16384) { int r = idx - 8192;  int n = r >> 6, k = r & 63;  v = pw1[k * HID + n]; }
    else if (idx < 32768) { int r = idx - 16384; int n = r >> 7, k = r & 127; v = lw2[k * HID + n]; }
    else                  { int r = idx - 32768; int n = r >> 7, k = r & 127; v = pw2[k * HID + n]; }
    we[idx] = f2bf(v);
}

// ==================== edge weights -> MFMA B-frag layout [l][t][lane][j], K padded to 32 ====================
__global__ void k_wconv_e(const float* __restrict__ ew, unsigned short* __restrict__ wte) {
    int idx = blockIdx.x * 256 + threadIdx.x;
    if (idx >= NLAYERS * 8 * 64 * 8) return;
    int j = idx & 7;
    int lane = (idx >> 3) & 63;
    int t = (idx >> 9) & 7;
    int l = idx >> 12;
    int k = (lane >> 4) * 8 + j;
    int feat = t * 16 + (lane & 15);
    float v = (k < EDGE_DIM) ? ew[l * EDGE_DIM * HID + k * HID + feat] : 0.0f;
    wte[idx] = f2bf(v);
}

// ==================== CSR build: histogram of dst ====================
__global__ void k_hist(const int* __restrict__ dsts, int* __restrict__ row_cnt) {
    int e = blockIdx.x * blockDim.x + threadIdx.x;
    if (e < N_EDGES) atomicAdd(&row_cnt[dsts[e]], 1);
}

// ==================== scan phase 1 ====================
__global__ __launch_bounds__(256) void k_scan1(const int* __restrict__ row_cnt,
                                               int* __restrict__ partial) {
    __shared__ int s[256];
    int t = threadIdx.x, b = blockIdx.x;
    int i0 = b * 512 + t;
    int v = 0;
    if (i0 < N_NODES) v += row_cnt[i0];
    if (i0 + 256 < N_NODES) v += row_cnt[i0 + 256];
    s[t] = v; __syncthreads();
    for (int off = 128; off > 0; off >>= 1) {
        if (t < off) s[t] += s[t + off];
        __syncthreads();
    }
    if (t == 0) partial[b] = s[0];
}

// ==================== scan phase 2 ====================
#define NCHUNK 98
__global__ __launch_bounds__(128) void k_scan2(int* __restrict__ partial) {
    __shared__ int s[128];
    int t = threadIdx.x;
    int v = (t < NCHUNK) ? partial[t] : 0;
    s[t] = v; __syncthreads();
    for (int off = 1; off < 128; off <<= 1) {
        int x = (t >= off) ? s[t - off] : 0;
        __syncthreads();
        s[t] += x;
        __syncthreads();
    }
    partial[t] = s[t] - v;   // exclusive
}

// ==================== scan phase 3 ====================
__global__ __launch_bounds__(512) void k_scan3(const int* __restrict__ row_cnt,
                                               const int* __restrict__ partial,
                                               int* __restrict__ row_start,
                                               int* __restrict__ row_fill) {
    __shared__ int s[512];
    int t = threadIdx.x, b = blockIdx.x;
    int i = b * 512 + t;
    int v = (i < N_NODES) ? row_cnt[i] : 0;
    s[t] = v; __syncthreads();
    for (int off = 1; off < 512; off <<= 1) {
        int x = (t >= off) ? s[t - off] : 0;
        __syncthreads();
        s[t] += x;
        __syncthreads();
    }
    int excl = s[t] - v + partial[b];
    if (i < N_NODES) { row_start[i] = excl; row_fill[i] = excl; }
}

// ==================== CSR fill: src + bf16-converted edge attrs in CSR order ====================
__global__ void k_fill(const int* __restrict__ srcs, const int* __restrict__ dsts,
                       const float* __restrict__ ea,
                       int* __restrict__ row_fill,
                       int* __restrict__ csr_src, unsigned short* __restrict__ cea) {
    int e = blockIdx.x * blockDim.x + threadIdx.x;
    if (e < N_EDGES) {
        int p = atomicAdd(&row_fill[dsts[e]], 1);
        csr_src[p] = srcs[e];
        const float* s = ea + (size_t)e * EDGE_DIM;
        bf8_t v0, v1;
        #pragma unroll
        for (int k = 0; k < 8; ++k) v0[k] = (short)f2bf(s[k]);
        #pragma unroll
        for (int k = 0; k < 8; ++k) v1[k] = (short)f2bf(s[8 + k]);
        *(bf8_t*)(cea + (size_t)p * EDGE_DIM) = v0;
        *(bf8_t*)(cea + (size_t)p * EDGE_DIM + 8) = v1;
    }
}

// ==================== encoder via MFMA: both paths, select at epilogue ====================
#define HS 136   // LDS row stride in shorts (128 + 8 pad)
__global__ __launch_bounds__(256) void k_encoder_mfma(
    const float* __restrict__ x,
    const unsigned short* __restrict__ we,
    const float* __restrict__ lb1, const float* __restrict__ lb2,
    const float* __restrict__ pb1, const float* __restrict__ pb2,
    float* __restrict__ H) {
    __shared__ short h1l[4 * 16 * HS];
    __shared__ short h1p[4 * 16 * HS];
    int w = threadIdx.x >> 6, lane = threadIdx.x & 63;
    int m = lane & 15, quad = lane >> 4;
    int nb = blockIdx.x * 64 + w * 16;
    short* hl = h1l + w * 16 * HS;
    short* hp = h1p + w * 16 * HS;
    int nclamp = nb + m; if (nclamp >= N_NODES) nclamp = N_NODES - 1;
    const float* xp = x + (size_t)nclamp * IN_DIM;

    f32x4 a1l[8], a1p[8];
    #pragma unroll
    for (int t = 0; t < 8; ++t) {
        float bl = lb1[t * 16 + m], bp = pb1[t * 16 + m];
        a1l[t] = (f32x4){bl, bl, bl, bl};
        a1p[t] = (f32x4){bp, bp, bp, bp};
    }
    #pragma unroll
    for (int s_ = 0; s_ < 2; ++s_) {
        int k0 = s_ * 32 + quad * 8;
        float4 a0 = *(const float4*)(xp + k0);
        float4 a1v = *(const float4*)(xp + k0 + 4);
        bf8_t af;
        af[0] = (short)f2bf(a0.x); af[1] = (short)f2bf(a0.y);
        af[2] = (short)f2bf(a0.z); af[3] = (short)f2bf(a0.w);
        af[4] = (short)f2bf(a1v.x); af[5] = (short)f2bf(a1v.y);
        af[6] = (short)f2bf(a1v.z); af[7] = (short)f2bf(a1v.w);
        #pragma unroll
        for (int t = 0; t < 8; ++t) {
            bf8_t bl = *(const bf8_t*)(we + (t * 16 + m) * 64 + k0);
            bf8_t bp = *(const bf8_t*)(we + 8192 + (t * 16 + m) * 64 + k0);
            a1l[t] = __builtin_amdgcn_mfma_f32_16x16x32_bf16(af, bl, a1l[t], 0, 0, 0);
            a1p[t] = __builtin_amdgcn_mfma_f32_16x16x32_bf16(af, bp, a1p[t], 0, 0, 0);
        }
    }
    #pragma unroll
    for (int t = 0; t < 8; ++t)
        #pragma unroll
        for (int r = 0; r < 4; ++r) {
            hl[(quad * 4 + r) * HS + t * 16 + m] = (short)f2bf(fmaxf(a1l[t][r], 0.0f));
            hp[(quad * 4 + r) * HS + t * 16 + m] = (short)f2bf(fmaxf(a1p[t][r], 0.0f));
        }
    __syncthreads();
    f32x4 a2l[8], a2p[8];
    #pragma unroll
    for (int t = 0; t < 8; ++t) {
        float bl = lb2[t * 16 + m], bp = pb2[t * 16 + m];
        a2l[t] = (f32x4){bl, bl, bl, bl};
        a2p[t] = (f32x4){bp, bp, bp, bp};
    }
    #pragma unroll
    for (int s_ = 0; s_ < 4; ++s_) {
        int k0 = s_ * 32 + quad * 8;
        bf8_t afl = *(const bf8_t*)(hl + m * HS + k0);
        bf8_t afp = *(const bf8_t*)(hp + m * HS + k0);
        #pragma unroll
        for (int t = 0; t < 8; ++t) {
            bf8_t bl = *(const bf8_t*)(we + 16384 + (t * 16 + m) * 128 + k0);
            bf8_t bp = *(const bf8_t*)(we + 32768 + (t * 16 + m) * 128 + k0);
            a2l[t] = __builtin_amdgcn_mfma_f32_16x16x32_bf16(afl, bl, a2l[t], 0, 0, 0);
            a2p[t] = __builtin_amdgcn_mfma_f32_16x16x32_bf16(afp, bp, a2p[t], 0, 0, 0);
        }
    }
    float flg[4];
    #pragma unroll
    for (int r = 0; r < 4; ++r) {
        int node = nb + quad * 4 + r; if (node >= N_NODES) node = N_NODES - 1;
        flg[r] = x[(size_t)node * IN_DIM + (IN_DIM - 1)];
    }
    #pragma unroll
    for (int t = 0; t < 8; ++t)
        #pragma unroll
        for (int r = 0; r < 4; ++r) {
            int node = nb + quad * 4 + r;
            if (node < N_NODES) {
                float v = (flg[r] > 0.5f) ? a2p[t][r] : a2l[t][r];
                H[(size_t)node * HID + t * 16 + m] = fmaxf(v, 0.0f);
            }
        }
}

// ==================== edge gather v5: MFMA edge-linear, one wave per node ====================
__global__ __launch_bounds__(256) void k_gather(
    const int* __restrict__ csr_src, const unsigned short* __restrict__ cea,
    const int* __restrict__ row_start, const int* __restrict__ row_end,
    const unsigned short* __restrict__ wte, const float* __restrict__ eb,
    const float* __restrict__ H, float* __restrict__ A) {
    int w = threadIdx.x >> 6, lane = threadIdx.x & 63;
    int m = lane & 15, quad = lane >> 4;
    int n = blockIdx.x * 4 + w;
    bf8_t bw[8];
    #pragma unroll
    for (int t = 0; t < 8; ++t)
        bw[t] = *(const bf8_t*)(wte + ((size_t)t * 64 + lane) * 8);
    float ebv[8];
    #pragma unroll
    for (int t = 0; t < 8; ++t) ebv[t] = eb[t * 16 + m];
    float acc[8];
    #pragma unroll
    for (int t = 0; t < 8; ++t) acc[t] = 0.0f;

    int p  = __builtin_amdgcn_readfirstlane(row_start[n]);
    int pe = __builtin_amdgcn_readfirstlane(row_end[n]);

    for (; p + 16 <= pe; p += 16) {
        bf8_t af = (bf8_t){0, 0, 0, 0, 0, 0, 0, 0};
        if (quad < 2)
            af = *(const bf8_t*)(cea + (size_t)(p + m) * EDGE_DIM + quad * 8);
        int sr[4];
        #pragma unroll
        for (int r = 0; r < 4; ++r) sr[r] = csr_src[p + quad * 4 + r];
        float h[8][4];
        #pragma unroll
        for (int r = 0; r < 4; ++r) {
            const float* hb = H + (size_t)sr[r] * HID + m;
            #pragma unroll
            for (int t = 0; t < 8; ++t) h[t][r] = hb[t * 16];
        }
        f32x4 d[8];
        #pragma unroll
        for (int t = 0; t < 8; ++t)
            d[t] = __builtin_amdgcn_mfma_f32_16x16x32_bf16(
                af, bw[t], (f32x4){ebv[t], ebv[t], ebv[t], ebv[t]}, 0, 0, 0);
        #pragma unroll
        for (int t = 0; t < 8; ++t)
            #pragma unroll
            for (int r = 0; r < 4; ++r)
                acc[t] += fmaxf(h[t][r] + d[t][r], 0.0f);
    }
    int rem = pe - p;
    if (rem > 0) {
        bf8_t af = (bf8_t){0, 0, 0, 0, 0, 0, 0, 0};
        if (quad < 2 && m < rem)
            af = *(const bf8_t*)(cea + (size_t)(p + m) * EDGE_DIM + quad * 8);
        int sr[4];
        #pragma unroll
        for (int r = 0; r < 4; ++r) {
            int idx = p + quad * 4 + r; if (idx >= pe) idx = pe - 1;
            sr[r] = csr_src[idx];
        }
        float h[8][4];
        #pragma unroll
        for (int r = 0; r < 4; ++r) {
            const float* hb = H + (size_t)sr[r] * HID + m;
            #pragma unroll
            for (int t = 0; t < 8; ++t) h[t][r] = hb[t * 16];
        }
        f32x4 d[8];
        #pragma unroll
        for (int t = 0; t < 8; ++t)
            d[t] = __builtin_amdgcn_mfma_f32_16x16x32_bf16(
                af, bw[t], (f32x4){ebv[t], ebv[t], ebv[t], ebv[t]}, 0, 0, 0);
        #pragma unroll
        for (int t = 0; t < 8; ++t)
            #pragma unroll
            for (int r = 0; r < 4; ++r)
                if (quad * 4 + r < rem) acc[t] += fmaxf(h[t][r] + d[t][r], 0.0f);
    }
    #pragma unroll
    for (int t = 0; t < 8; ++t) {
        acc[t] += __shfl_xor(acc[t], 16);
        acc[t] += __shfl_xor(acc[t], 32);
    }
    int t0 = quad * 2, t1 = quad * 2 + 1;
    size_t base = (size_t)n * HID;
    A[base + t0 * 16 + m] = acc[t0] + H[base + t0 * 16 + m];
    A[base + t1 * 16 + m] = acc[t1] + H[base + t1 * 16 + m];
}

// ==================== node MLP via MFMA (proven in R6) ====================
#define MLP_NODES_PER_BLOCK 64
__global__ __launch_bounds__(256) void k_mlp_mfma(
    const float* __restrict__ A, const int* __restrict__ batch,
    const unsigned short* __restrict__ wt1, const unsigned short* __restrict__ wt2,
    const float* __restrict__ b1, const float* __restrict__ b2,
    float* __restrict__ H, float* __restrict__ gsum, float* __restrict__ gsq) {
    __shared__ short h1s[4 * 16 * HS];
    int w = threadIdx.x >> 6;
    int lane = threadIdx.x & 63;
    int m = lane & 15;
    int quad = lane >> 4;
    int nb = blockIdx.x * MLP_NODES_PER_BLOCK + w * 16;
    short* hw = h1s + w * 16 * HS;

    int nclamp = nb + m; if (nclamp >= N_NODES) nclamp = N_NODES - 1;
    const float* Ap = A + (size_t)nclamp * HID;
    f32x4 acc1[8];
    #pragma unroll
    for (int t = 0; t < 8; ++t) {
        float bv = b1[t * 16 + m];
        acc1[t] = (f32x4){bv, bv, bv, bv};
    }
    #pragma unroll
    for (int s_ = 0; s_ < 4; ++s_) {
        int k0 = s_ * 32 + quad * 8;
        float4 a0 = *(const float4*)(Ap + k0);
        float4 a1 = *(const float4*)(Ap + k0 + 4);
        bf8_t af;
        af[0] = (short)f2bf(a0.x); af[1] = (short)f2bf(a0.y);
        af[2] = (short)f2bf(a0.z); af[3] = (short)f2bf(a0.w);
        af[4] = (short)f2bf(a1.x); af[5] = (short)f2bf(a1.y);
        af[6] = (short)f2bf(a1.z); af[7] = (short)f2bf(a1.w);
        #pragma unroll
        for (int t = 0; t < 8; ++t) {
            bf8_t bf = *(const bf8_t*)(wt1 + (t * 16 + m) * HID + k0);
            acc1[t] = __builtin_amdgcn_mfma_f32_16x16x32_bf16(af, bf, acc1[t], 0, 0, 0);
        }
    }
    #pragma unroll
    for (int t = 0; t < 8; ++t)
        #pragma unroll
        for (int r = 0; r < 4; ++r) {
            float v = fmaxf(acc1[t][r], 0.0f);
            hw[(quad * 4 + r) * HS + t * 16 + m] = (short)f2bf(v);
        }
    __syncthreads();
    f32x4 acc2[8];
    #pragma unroll
    for (int t = 0; t < 8; ++t) {
        float bv = b2[t * 16 + m];
        acc2[t] = (f32x4){bv, bv, bv, bv};
    }
    #pragma unroll
    for (int s_ = 0; s_ < 4; ++s_) {
        int k0 = s_ * 32 + quad * 8;
        bf8_t af = *(const bf8_t*)(hw + m * HS + k0);
        #pragma unroll
        for (int t = 0; t < 8; ++t) {
            bf8_t bf = *(const bf8_t*)(wt2 + (t * 16 + m) * HID + k0);
            acc2[t] = __builtin_amdgcn_mfma_f32_16x16x32_bf16(af, bf, acc2[t], 0, 0, 0);
        }
    }
    #pragma unroll
    for (int t = 0; t < 8; ++t)
        #pragma unroll
        for (int r = 0; r < 4; ++r) {
            int node = nb + quad * 4 + r;
            if (node < N_NODES) H[(size_t)node * HID + t * 16 + m] = acc2[t][r];
        }
    int blast = nb + 15 < N_NODES ? batch[nb + 15] : -1;
    int g0 = batch[nb < N_NODES ? nb : N_NODES - 1];
    if (nb + 15 < N_NODES && g0 == blast) {
        #pragma unroll
        for (int t = 0; t < 8; ++t) {
            float s = 0.0f, q = 0.0f;
            #pragma unroll
            for (int r = 0; r < 4; ++r) { float v = acc2[t][r]; s += v; q += v * v; }
            s += __shfl_xor(s, 16); q += __shfl_xor(q, 16);
            s += __shfl_xor(s, 32); q += __shfl_xor(q, 32);
            if (quad == 0) {
                atomicAdd(&gsum[g0 * HID + t * 16 + m], s);
                atomicAdd(&gsq[g0 * HID + t * 16 + m], q);
            }
        }
    } else {
        #pragma unroll
        for (int t = 0; t < 8; ++t)
            #pragma unroll
            for (int r = 0; r < 4; ++r) {
                int node = nb + quad * 4 + r;
                if (node < N_NODES) {
                    int g = batch[node];
                    float v = acc2[t][r];
                    atomicAdd(&gsum[g * HID + t * 16 + m], v);
                    atomicAdd(&gsq[g * HID + t * 16 + m], v * v);
                }
            }
    }
}

// ==================== GraphNorm stats (re-zeros moments) ====================
__global__ __launch_bounds__(HID) void k_stats(
    float* __restrict__ gsum, float* __restrict__ gsq,
    const float* __restrict__ cnt,
    const float* __restrict__ gw, const float* __restrict__ gb,
    const float* __restrict__ gms,
    float* __restrict__ sc, float* __restrict__ of) {
    int g = blockIdx.x;
    int t = threadIdx.x;
    float c = fmaxf(cnt[g], 1.0f);
    float mean = gsum[g * HID + t] / c;
    float msq  = gsq[g * HID + t] / c;
    float ms = gms[t];
    float var = msq - mean * mean * ms * (2.0f - ms);
    var = fmaxf(var, 0.0f);
    float istd = rsqrtf(var + EPS);
    float s = gw[t] * istd;
    sc[g * HID + t] = s;
    of[g * HID + t] = gb[t] - s * mean * ms;
    gsum[g * HID + t] = 0.0f;
    gsq[g * HID + t]  = 0.0f;
}

// ==================== normalize + relu (+ pooled global_add on last layer) ====================
#define NORM_N 8
__global__ __launch_bounds__(HID) void k_norm(
    float* __restrict__ H, const int* __restrict__ batch,
    const float* __restrict__ sc, const float* __restrict__ of,
    float* __restrict__ pool, int accumulate) {
    int n0 = blockIdx.x * NORM_N;
    int t = threadIdx.x;
    int g0 = batch[n0], gN = batch[n0 + NORM_N - 1];
    if (g0 == gN) {
        float ssc = sc[g0 * HID + t], sof = of[g0 * HID + t];
        float ps = 0.0f;
        #pragma unroll
        for (int i = 0; i < NORM_N; ++i) {
            float v = fmaxf(H[(n0 + i) * HID + t] * ssc + sof, 0.0f);
            H[(n0 + i) * HID + t] = v;
            ps += v;
        }
        if (accumulate) atomicAdd(&pool[g0 * HID + t], ps);
    } else {
        #pragma unroll
        for (int i = 0; i < NORM_N; ++i) {
            int g = batch[n0 + i];
            float v = fmaxf(H[(n0 + i) * HID + t] * sc[g * HID + t] + of[g * HID + t], 0.0f);
            H[(n0 + i) * HID + t] = v;
            if (accumulate) atomicAdd(&pool[g * HID + t], v);
        }
    }
}

// ==================== output head ====================
__global__ __launch_bounds__(HID) void k_head(
    const float* __restrict__ pool,
    const float* __restrict__ fw1, const float* __restrict__ fb1,
    const float* __restrict__ fw2, const float* __restrict__ fb2,
    float* __restrict__ out) {
    __shared__ float ps[HID];
    __shared__ float red[2];
    int g = blockIdx.x;
    int t = threadIdx.x;
    ps[t] = pool[g * HID + t];
    __syncthreads();
    float acc = fb1[t];
    #pragma unroll 4
    for (int k = 0; k < HID; ++k) acc = fmaf(ps[k], fw1[k * HID + t], acc);
    float p = fmaxf(acc, 0.0f) * fw2[t];
    #pragma unroll
    for (int off = 32; off > 0; off >>= 1) p += __shfl_down(p, off, 64);
    if ((t & 63) == 0) red[t >> 6] = p;
    __syncthreads();
    if (t == 0) out[g] = red[0] + red[1] + fb2[0];
}

extern "C" void kernel_launch(void* const* d_in, const int* in_sizes, int n_in,
                              void* d_out, int out_size, void* d_ws, size_t ws_size,
                              hipStream_t stream) {
    const float* x     = (const float*)d_in[0];
    const int*   ei    = (const int*)d_in[1];
    const float* ea    = (const float*)d_in[2];
    const int*   batch = (const int*)d_in[3];
    const float* lw1 = (const float*)d_in[4];
    const float* lb1 = (const float*)d_in[5];
    const float* lw2 = (const float*)d_in[6];
    const float* lb2 = (const float*)d_in[7];
    const float* pw1 = (const float*)d_in[8];
    const float* pb1 = (const float*)d_in[9];
    const float* pw2 = (const float*)d_in[10];
    const float* pb2 = (const float*)d_in[11];
    const float* ew  = (const float*)d_in[12];
    const float* eb  = (const float*)d_in[13];
    const float* nw1 = (const float*)d_in[14];
    const float* nb1 = (const float*)d_in[15];
    const float* nw2 = (const float*)d_in[16];
    const float* nb2 = (const float*)d_in[17];
    const float* gw  = (const float*)d_in[18];
    const float* gb  = (const float*)d_in[19];
    const float* gms = (const float*)d_in[20];
    const float* fw1 = (const float*)d_in[21];
    const float* fb1 = (const float*)d_in[22];
    const float* fw2 = (const float*)d_in[23];
    const float* fb2 = (const float*)d_in[24];
    float* out = (float*)d_out;

    float* ws   = (float*)d_ws;
    float* H    = ws;                          // 6,400,000 f
    float* A    = H    + (size_t)N_NODES * HID;// 6,400,000 f
    float* gsum = A    + (size_t)N_NODES * HID;
    float* gsq  = gsum + NGRAPH * HID;
    float* sc   = gsq  + NGRAPH * HID;
    float* of   = sc   + NGRAPH * HID;
    float* pool = of   + NGRAPH * HID;
    float* cnt  = pool + NGRAPH * HID;         // 128 f
    int* row_cnt   = (int*)(cnt + NGRAPH);     // 50000
    int* row_start = row_cnt + N_NODES;        // 50000
    int* row_fill  = row_start + N_NODES;      // 50000
    int* partial   = row_fill + N_NODES;       // 128
    int* csr_src   = partial + 128;            // 800000
    unsigned short* cea  = (unsigned short*)(csr_src + N_EDGES); // 12,800,000 bf16 (25.6 MB)
    unsigned short* wt   = cea + (size_t)N_EDGES * EDGE_DIM;     // 98304
    unsigned short* wenc = wt + NLAYERS * 2 * HID * HID;         // 49152
    unsigned short* wte  = wenc + 49152;                         // 12288

    const int* srcs = ei;
    const int* dsts = ei + N_EDGES;

    // ---- init + CSR build + weight conversion ----
    k_init<<<(N_NODES + 255) / 256, 256, 0, stream>>>(row_cnt, pool, gsum, gsq);
    k_count<<<1, NGRAPH, 0, stream>>>(batch, cnt);
    k_wconv<<<(NLAYERS * 2 * HID * HID + 255) / 256, 256, 0, stream>>>(nw1, nw2, wt);
    k_wconv_enc<<<(49152 + 255) / 256, 256, 0, stream>>>(lw1, pw1, lw2, pw2, wenc);
    k_wconv_e<<<(NLAYERS * 8 * 64 * 8 + 255) / 256, 256, 0, stream>>>(ew, wte);
    k_hist<<<(N_EDGES + 255) / 256, 256, 0, stream>>>(dsts, row_cnt);
    k_scan1<<<NCHUNK, 256, 0, stream>>>(row_cnt, partial);
    k_scan2<<<1, 128, 0, stream>>>(partial);
    k_scan3<<<NCHUNK, 512, 0, stream>>>(row_cnt, partial, row_start, row_fill);
    k_fill<<<(N_EDGES + 255) / 256, 256, 0, stream>>>(srcs, dsts, ea, row_fill,
                                                      csr_src, cea);

    // ---- encoder (MFMA) ----
    k_encoder_mfma<<<(N_NODES + 63) / 64, 256, 0, stream>>>(
        x, wenc, lb1, lb2, pb1, pb2, H);

    // ---- layers ----
    int mlp_blocks = (N_NODES + MLP_NODES_PER_BLOCK - 1) / MLP_NODES_PER_BLOCK;
    for (int l = 0; l < NLAYERS; ++l) {
        k_gather<<<N_NODES / 4, 256, 0, stream>>>(
            csr_src, cea, row_start, row_fill,
            wte + (size_t)l * 4096, eb + l * HID, H, A);
        k_mlp_mfma<<<mlp_blocks, 256, 0, stream>>>(
            A, batch,
            wt + (size_t)l * 2 * HID * HID,
            wt + (size_t)l * 2 * HID * HID + HID * HID,
            nb1 + l * HID, nb2 + l * HID, H, gsum, gsq);
        k_stats<<<NGRAPH, HID, 0, stream>>>(gsum, gsq, cnt,
                                            gw + l * HID, gb + l * HID, gms + l * HID,
                                            sc, of);
        k_norm<<<N_NODES / NORM_N, HID, 0, stream>>>(
            H, batch, sc, of, pool, (l == NLAYERS - 1) ? 1 : 0);
    }
    k_head<<<NGRAPH, HID, 0, stream>>>(pool, fw1, fb1, fw2, fb2, out);
}

// Round 8
// 707.138 us; speedup vs baseline: 1.5209x; 1.0399x over previous
//
#include <hip/hip_runtime.h>

#define N_NODES 50000
#define N_EDGES 800000
#define IN_DIM  64
#define EDGE_DIM 16
#define HID     128
#define NLAYERS 3
#define NGRAPH  128
#define EPS     1e-5f

typedef __attribute__((ext_vector_type(8))) short bf8_t;
typedef __attribute__((ext_vector_type(4))) float f32x4;

__device__ __forceinline__ unsigned short f2bf(float x) {
    unsigned u = __float_as_uint(x);
    unsigned r = u + 0x7fffu + ((u >> 16) & 1u);   // round-to-nearest-even
    return (unsigned short)(r >> 16);
}
__device__ __forceinline__ float bf2f(unsigned short v) {
    return __uint_as_float(((unsigned)v) << 16);
}

// ==================== init ====================
__global__ void k_init(int* __restrict__ row_cnt, float* __restrict__ pool,
                       float* __restrict__ gsum, float* __restrict__ gsq) {
    int i = blockIdx.x * blockDim.x + threadIdx.x;
    if (i < N_NODES) row_cnt[i] = 0;
    if (i < NGRAPH * HID) { pool[i] = 0.0f; gsum[i] = 0.0f; gsq[i] = 0.0f; }
}

// ==================== per-graph node counts via binary search ====================
__global__ __launch_bounds__(NGRAPH) void k_count(const int* __restrict__ batch,
                                                  float* __restrict__ cnt) {
    int g = threadIdx.x;
    int lo = 0, hi = N_NODES;
    while (lo < hi) { int mid = (lo + hi) >> 1; if (batch[mid] < g) lo = mid + 1; else hi = mid; }
    int a = lo;
    lo = 0; hi = N_NODES;
    while (lo < hi) { int mid = (lo + hi) >> 1; if (batch[mid] < g + 1) lo = mid + 1; else hi = mid; }
    cnt[g] = (float)(lo - a);
}

// ==================== nn weights -> bf16 transposed [l][which][n][k] ====================
__global__ void k_wconv(const float* __restrict__ nw1, const float* __restrict__ nw2,
                        unsigned short* __restrict__ wt) {
    int idx = blockIdx.x * 256 + threadIdx.x;
    if (idx >= NLAYERS * 2 * HID * HID) return;
    int k = idx & 127;
    int n = (idx >> 7) & 127;
    int which = (idx >> 14) & 1;
    int l = idx >> 15;
    const float* w = (which == 0 ? nw1 : nw2) + l * HID * HID;
    wt[idx] = f2bf(w[k * HID + n]);
}

// ==================== encoder weights -> bf16 transposed ====================
__global__ void k_wconv_enc(const float* __restrict__ lw1, const float* __restrict__ pw1,
                            const float* __restrict__ lw2, const float* __restrict__ pw2,
                            unsigned short* __restrict__ we) {
    int idx = blockIdx.x * 256 + threadIdx.x;
    if (idx >= 49152) return;
    float v;
    if (idx < 8192)       { int n = idx >> 6, k = idx & 63;            v = lw1[k * HID + n]; }
    else if (idx < 16384) { int r = idx - 8192;  int n = r >> 6, k = r & 63;  v = pw1[k * HID + n]; }
    else if (idx < 32768) { int r = idx - 16384; int n = r >> 7, k = r & 127; v = lw2[k * HID + n]; }
    else                  { int r = idx - 32768; int n = r >> 7, k = r & 127; v = pw2[k * HID + n]; }
    we[idx] = f2bf(v);
}

// ==================== edge weights -> MFMA B-frag layout [l][t][lane][j], K padded to 32 ====================
__global__ void k_wconv_e(const float* __restrict__ ew, unsigned short* __restrict__ wte) {
    int idx = blockIdx.x * 256 + threadIdx.x;
    if (idx >= NLAYERS * 8 * 64 * 8) return;
    int j = idx & 7;
    int lane = (idx >> 3) & 63;
    int t = (idx >> 9) & 7;
    int l = idx >> 12;
    int k = (lane >> 4) * 8 + j;
    int feat = t * 16 + (lane & 15);
    float v = (k < EDGE_DIM) ? ew[l * EDGE_DIM * HID + k * HID + feat] : 0.0f;
    wte[idx] = f2bf(v);
}

// ==================== CSR build: histogram of dst ====================
__global__ void k_hist(const int* __restrict__ dsts, int* __restrict__ row_cnt) {
    int e = blockIdx.x * blockDim.x + threadIdx.x;
    if (e < N_EDGES) atomicAdd(&row_cnt[dsts[e]], 1);
}

// ==================== scan phase 1 ====================
__global__ __launch_bounds__(256) void k_scan1(const int* __restrict__ row_cnt,
                                               int* __restrict__ partial) {
    __shared__ int s[256];
    int t = threadIdx.x, b = blockIdx.x;
    int i0 = b * 512 + t;
    int v = 0;
    if (i0 < N_NODES) v += row_cnt[i0];
    if (i0 + 256 < N_NODES) v += row_cnt[i0 + 256];
    s[t] = v; __syncthreads();
    for (int off = 128; off > 0; off >>= 1) {
        if (t < off) s[t] += s[t + off];
        __syncthreads();
    }
    if (t == 0) partial[b] = s[0];
}

// ==================== scan phase 2 ====================
#define NCHUNK 98
__global__ __launch_bounds__(128) void k_scan2(int* __restrict__ partial) {
    __shared__ int s[128];
    int t = threadIdx.x;
    int v = (t < NCHUNK) ? partial[t] : 0;
    s[t] = v; __syncthreads();
    for (int off = 1; off < 128; off <<= 1) {
        int x = (t >= off) ? s[t - off] : 0;
        __syncthreads();
        s[t] += x;
        __syncthreads();
    }
    partial[t] = s[t] - v;   // exclusive
}

// ==================== scan phase 3 ====================
__global__ __launch_bounds__(512) void k_scan3(const int* __restrict__ row_cnt,
                                               const int* __restrict__ partial,
                                               int* __restrict__ row_start,
                                               int* __restrict__ row_fill) {
    __shared__ int s[512];
    int t = threadIdx.x, b = blockIdx.x;
    int i = b * 512 + t;
    int v = (i < N_NODES) ? row_cnt[i] : 0;
    s[t] = v; __syncthreads();
    for (int off = 1; off < 512; off <<= 1) {
        int x = (t >= off) ? s[t - off] : 0;
        __syncthreads();
        s[t] += x;
        __syncthreads();
    }
    int excl = s[t] - v + partial[b];
    if (i < N_NODES) { row_start[i] = excl; row_fill[i] = excl; }
}

// ==================== CSR fill: src + bf16 edge attrs in CSR order ====================
__global__ void k_fill(const int* __restrict__ srcs, const int* __restrict__ dsts,
                       const float* __restrict__ ea,
                       int* __restrict__ row_fill,
                       int* __restrict__ csr_src, unsigned short* __restrict__ cea) {
    int e = blockIdx.x * blockDim.x + threadIdx.x;
    if (e < N_EDGES) {
        int p = atomicAdd(&row_fill[dsts[e]], 1);
        csr_src[p] = srcs[e];
        const float* s = ea + (size_t)e * EDGE_DIM;
        bf8_t v0, v1;
        #pragma unroll
        for (int k = 0; k < 8; ++k) v0[k] = (short)f2bf(s[k]);
        #pragma unroll
        for (int k = 0; k < 8; ++k) v1[k] = (short)f2bf(s[8 + k]);
        *(bf8_t*)(cea + (size_t)p * EDGE_DIM) = v0;
        *(bf8_t*)(cea + (size_t)p * EDGE_DIM + 8) = v1;
    }
}

// ==================== encoder via MFMA -> writes Hbp (bf16, permuted [n][m][t]) ====================
#define HS 136   // LDS row stride in shorts
__global__ __launch_bounds__(256) void k_encoder_mfma(
    const float* __restrict__ x,
    const unsigned short* __restrict__ we,
    const float* __restrict__ lb1, const float* __restrict__ lb2,
    const float* __restrict__ pb1, const float* __restrict__ pb2,
    unsigned short* __restrict__ Hbp) {
    __shared__ short h1l[4 * 16 * HS];
    __shared__ short h1p[4 * 16 * HS];
    int w = threadIdx.x >> 6, lane = threadIdx.x & 63;
    int m = lane & 15, quad = lane >> 4;
    int nb = blockIdx.x * 64 + w * 16;
    short* hl = h1l + w * 16 * HS;
    short* hp = h1p + w * 16 * HS;
    int nclamp = nb + m; if (nclamp >= N_NODES) nclamp = N_NODES - 1;
    const float* xp = x + (size_t)nclamp * IN_DIM;

    f32x4 a1l[8], a1p[8];
    #pragma unroll
    for (int t = 0; t < 8; ++t) {
        float bl = lb1[t * 16 + m], bp = pb1[t * 16 + m];
        a1l[t] = (f32x4){bl, bl, bl, bl};
        a1p[t] = (f32x4){bp, bp, bp, bp};
    }
    #pragma unroll
    for (int s_ = 0; s_ < 2; ++s_) {
        int k0 = s_ * 32 + quad * 8;
        float4 a0 = *(const float4*)(xp + k0);
        float4 a1v = *(const float4*)(xp + k0 + 4);
        bf8_t af;
        af[0] = (short)f2bf(a0.x); af[1] = (short)f2bf(a0.y);
        af[2] = (short)f2bf(a0.z); af[3] = (short)f2bf(a0.w);
        af[4] = (short)f2bf(a1v.x); af[5] = (short)f2bf(a1v.y);
        af[6] = (short)f2bf(a1v.z); af[7] = (short)f2bf(a1v.w);
        #pragma unroll
        for (int t = 0; t < 8; ++t) {
            bf8_t bl = *(const bf8_t*)(we + (t * 16 + m) * 64 + k0);
            bf8_t bp = *(const bf8_t*)(we + 8192 + (t * 16 + m) * 64 + k0);
            a1l[t] = __builtin_amdgcn_mfma_f32_16x16x32_bf16(af, bl, a1l[t], 0, 0, 0);
            a1p[t] = __builtin_amdgcn_mfma_f32_16x16x32_bf16(af, bp, a1p[t], 0, 0, 0);
        }
    }
    #pragma unroll
    for (int t = 0; t < 8; ++t)
        #pragma unroll
        for (int r = 0; r < 4; ++r) {
            hl[(quad * 4 + r) * HS + t * 16 + m] = (short)f2bf(fmaxf(a1l[t][r], 0.0f));
            hp[(quad * 4 + r) * HS + t * 16 + m] = (short)f2bf(fmaxf(a1p[t][r], 0.0f));
        }
    __syncthreads();
    f32x4 a2l[8], a2p[8];
    #pragma unroll
    for (int t = 0; t < 8; ++t) {
        float bl = lb2[t * 16 + m], bp = pb2[t * 16 + m];
        a2l[t] = (f32x4){bl, bl, bl, bl};
        a2p[t] = (f32x4){bp, bp, bp, bp};
    }
    #pragma unroll
    for (int s_ = 0; s_ < 4; ++s_) {
        int k0 = s_ * 32 + quad * 8;
        bf8_t afl = *(const bf8_t*)(hl + m * HS + k0);
        bf8_t afp = *(const bf8_t*)(hp + m * HS + k0);
        #pragma unroll
        for (int t = 0; t < 8; ++t) {
            bf8_t bl = *(const bf8_t*)(we + 16384 + (t * 16 + m) * 128 + k0);
            bf8_t bp = *(const bf8_t*)(we + 32768 + (t * 16 + m) * 128 + k0);
            a2l[t] = __builtin_amdgcn_mfma_f32_16x16x32_bf16(afl, bl, a2l[t], 0, 0, 0);
            a2p[t] = __builtin_amdgcn_mfma_f32_16x16x32_bf16(afp, bp, a2p[t], 0, 0, 0);
        }
    }
    #pragma unroll
    for (int r = 0; r < 4; ++r) {
        int node = nb + quad * 4 + r;
        if (node < N_NODES) {
            float flg = x[(size_t)node * IN_DIM + (IN_DIM - 1)];
            bool prot = flg > 0.5f;
            bf8_t o;
            #pragma unroll
            for (int t = 0; t < 8; ++t) {
                float v = prot ? a2p[t][r] : a2l[t][r];
                o[t] = (short)f2bf(fmaxf(v, 0.0f));
            }
            *(bf8_t*)(Hbp + (size_t)node * HID + m * 8) = o;
        }
    }
}

// ==================== edge gather v6: bf16 permuted H rows, 16B/row/lane ====================
__global__ __launch_bounds__(256) void k_gather(
    const int* __restrict__ csr_src, const unsigned short* __restrict__ cea,
    const int* __restrict__ row_start, const int* __restrict__ row_end,
    const unsigned short* __restrict__ wte, const float* __restrict__ eb,
    const unsigned short* __restrict__ Hbp, float* __restrict__ A) {
    int w = threadIdx.x >> 6, lane = threadIdx.x & 63;
    int m = lane & 15, quad = lane >> 4;
    int n = blockIdx.x * 4 + w;
    bf8_t bw[8];
    #pragma unroll
    for (int t = 0; t < 8; ++t)
        bw[t] = *(const bf8_t*)(wte + ((size_t)t * 64 + lane) * 8);
    float ebv[8];
    #pragma unroll
    for (int t = 0; t < 8; ++t) ebv[t] = eb[t * 16 + m];
    float acc[8];
    #pragma unroll
    for (int t = 0; t < 8; ++t) acc[t] = 0.0f;

    int p  = __builtin_amdgcn_readfirstlane(row_start[n]);
    int pe = __builtin_amdgcn_readfirstlane(row_end[n]);

    for (; p + 16 <= pe; p += 16) {
        bf8_t af = (bf8_t){0, 0, 0, 0, 0, 0, 0, 0};
        if (quad < 2)
            af = *(const bf8_t*)(cea + (size_t)(p + m) * EDGE_DIM + quad * 8);
        int sr[4];
        #pragma unroll
        for (int r = 0; r < 4; ++r) sr[r] = csr_src[p + quad * 4 + r];
        bf8_t hrow[4];
        #pragma unroll
        for (int r = 0; r < 4; ++r)
            hrow[r] = *(const bf8_t*)(Hbp + (size_t)sr[r] * HID + m * 8);
        f32x4 d[8];
        #pragma unroll
        for (int t = 0; t < 8; ++t)
            d[t] = __builtin_amdgcn_mfma_f32_16x16x32_bf16(
                af, bw[t], (f32x4){ebv[t], ebv[t], ebv[t], ebv[t]}, 0, 0, 0);
        #pragma unroll
        for (int t = 0; t < 8; ++t)
            #pragma unroll
            for (int r = 0; r < 4; ++r)
                acc[t] += fmaxf(bf2f((unsigned short)hrow[r][t]) + d[t][r], 0.0f);
    }
    int rem = pe - p;
    if (rem > 0) {
        bf8_t af = (bf8_t){0, 0, 0, 0, 0, 0, 0, 0};
        if (quad < 2 && m < rem)
            af = *(const bf8_t*)(cea + (size_t)(p + m) * EDGE_DIM + quad * 8);
        int sr[4];
        #pragma unroll
        for (int r = 0; r < 4; ++r) {
            int idx = p + quad * 4 + r; if (idx >= pe) idx = pe - 1;
            sr[r] = csr_src[idx];
        }
        bf8_t hrow[4];
        #pragma unroll
        for (int r = 0; r < 4; ++r)
            hrow[r] = *(const bf8_t*)(Hbp + (size_t)sr[r] * HID + m * 8);
        f32x4 d[8];
        #pragma unroll
        for (int t = 0; t < 8; ++t)
            d[t] = __builtin_amdgcn_mfma_f32_16x16x32_bf16(
                af, bw[t], (f32x4){ebv[t], ebv[t], ebv[t], ebv[t]}, 0, 0, 0);
        #pragma unroll
        for (int t = 0; t < 8; ++t)
            #pragma unroll
            for (int r = 0; r < 4; ++r)
                if (quad * 4 + r < rem)
                    acc[t] += fmaxf(bf2f((unsigned short)hrow[r][t]) + d[t][r], 0.0f);
    }
    #pragma unroll
    for (int t = 0; t < 8; ++t) {
        acc[t] += __shfl_xor(acc[t], 16);
        acc[t] += __shfl_xor(acc[t], 32);
    }
    // self term from Hbp (bf16): feats t0*16+m, t1*16+m are consecutive in Hbp
    int t0 = quad * 2, t1 = quad * 2 + 1;
    const unsigned short* selfp = Hbp + (size_t)n * HID + m * 8;
    float s0 = bf2f(selfp[t0]);
    float s1 = bf2f(selfp[t1]);
    size_t base = (size_t)n * HID;
    A[base + t0 * 16 + m] = acc[t0] + s0;
    A[base + t1 * 16 + m] = acc[t1] + s1;
}

// ==================== node MLP via MFMA ====================
#define MLP_NODES_PER_BLOCK 64
__global__ __launch_bounds__(256) void k_mlp_mfma(
    const float* __restrict__ A, const int* __restrict__ batch,
    const unsigned short* __restrict__ wt1, const unsigned short* __restrict__ wt2,
    const float* __restrict__ b1, const float* __restrict__ b2,
    float* __restrict__ H, float* __restrict__ gsum, float* __restrict__ gsq) {
    __shared__ short h1s[4 * 16 * HS];
    int w = threadIdx.x >> 6;
    int lane = threadIdx.x & 63;
    int m = lane & 15;
    int quad = lane >> 4;
    int nb = blockIdx.x * MLP_NODES_PER_BLOCK + w * 16;
    short* hw = h1s + w * 16 * HS;

    int nclamp = nb + m; if (nclamp >= N_NODES) nclamp = N_NODES - 1;
    const float* Ap = A + (size_t)nclamp * HID;
    f32x4 acc1[8];
    #pragma unroll
    for (int t = 0; t < 8; ++t) {
        float bv = b1[t * 16 + m];
        acc1[t] = (f32x4){bv, bv, bv, bv};
    }
    #pragma unroll
    for (int s_ = 0; s_ < 4; ++s_) {
        int k0 = s_ * 32 + quad * 8;
        float4 a0 = *(const float4*)(Ap + k0);
        float4 a1 = *(const float4*)(Ap + k0 + 4);
        bf8_t af;
        af[0] = (short)f2bf(a0.x); af[1] = (short)f2bf(a0.y);
        af[2] = (short)f2bf(a0.z); af[3] = (short)f2bf(a0.w);
        af[4] = (short)f2bf(a1.x); af[5] = (short)f2bf(a1.y);
        af[6] = (short)f2bf(a1.z); af[7] = (short)f2bf(a1.w);
        #pragma unroll
        for (int t = 0; t < 8; ++t) {
            bf8_t bf = *(const bf8_t*)(wt1 + (t * 16 + m) * HID + k0);
            acc1[t] = __builtin_amdgcn_mfma_f32_16x16x32_bf16(af, bf, acc1[t], 0, 0, 0);
        }
    }
    #pragma unroll
    for (int t = 0; t < 8; ++t)
        #pragma unroll
        for (int r = 0; r < 4; ++r) {
            float v = fmaxf(acc1[t][r], 0.0f);
            hw[(quad * 4 + r) * HS + t * 16 + m] = (short)f2bf(v);
        }
    __syncthreads();
    f32x4 acc2[8];
    #pragma unroll
    for (int t = 0; t < 8; ++t) {
        float bv = b2[t * 16 + m];
        acc2[t] = (f32x4){bv, bv, bv, bv};
    }
    #pragma unroll
    for (int s_ = 0; s_ < 4; ++s_) {
        int k0 = s_ * 32 + quad * 8;
        bf8_t af = *(const bf8_t*)(hw + m * HS + k0);
        #pragma unroll
        for (int t = 0; t < 8; ++t) {
            bf8_t bf = *(const bf8_t*)(wt2 + (t * 16 + m) * HID + k0);
            acc2[t] = __builtin_amdgcn_mfma_f32_16x16x32_bf16(af, bf, acc2[t], 0, 0, 0);
        }
    }
    #pragma unroll
    for (int t = 0; t < 8; ++t)
        #pragma unroll
        for (int r = 0; r < 4; ++r) {
            int node = nb + quad * 4 + r;
            if (node < N_NODES) H[(size_t)node * HID + t * 16 + m] = acc2[t][r];
        }
    int blast = nb + 15 < N_NODES ? batch[nb + 15] : -1;
    int g0 = batch[nb < N_NODES ? nb : N_NODES - 1];
    if (nb + 15 < N_NODES && g0 == blast) {
        #pragma unroll
        for (int t = 0; t < 8; ++t) {
            float s = 0.0f, q = 0.0f;
            #pragma unroll
            for (int r = 0; r < 4; ++r) { float v = acc2[t][r]; s += v; q += v * v; }
            s += __shfl_xor(s, 16); q += __shfl_xor(q, 16);
            s += __shfl_xor(s, 32); q += __shfl_xor(q, 32);
            if (quad == 0) {
                atomicAdd(&gsum[g0 * HID + t * 16 + m], s);
                atomicAdd(&gsq[g0 * HID + t * 16 + m], q);
            }
        }
    } else {
        #pragma unroll
        for (int t = 0; t < 8; ++t)
            #pragma unroll
            for (int r = 0; r < 4; ++r) {
                int node = nb + quad * 4 + r;
                if (node < N_NODES) {
                    int g = batch[node];
                    float v = acc2[t][r];
                    atomicAdd(&gsum[g * HID + t * 16 + m], v);
                    atomicAdd(&gsq[g * HID + t * 16 + m], v * v);
                }
            }
    }
}

// ==================== GraphNorm stats (re-zeros moments) ====================
__global__ __launch_bounds__(HID) void k_stats(
    float* __restrict__ gsum, float* __restrict__ gsq,
    const float* __restrict__ cnt,
    const float* __restrict__ gw, const float* __restrict__ gb,
    const float* __restrict__ gms,
    float* __restrict__ sc, float* __restrict__ of) {
    int g = blockIdx.x;
    int t = threadIdx.x;
    float c = fmaxf(cnt[g], 1.0f);
    float mean = gsum[g * HID + t] / c;
    float msq  = gsq[g * HID + t] / c;
    float ms = gms[t];
    float var = msq - mean * mean * ms * (2.0f - ms);
    var = fmaxf(var, 0.0f);
    float istd = rsqrtf(var + EPS);
    float s = gw[t] * istd;
    sc[g * HID + t] = s;
    of[g * HID + t] = gb[t] - s * mean * ms;
    gsum[g * HID + t] = 0.0f;
    gsq[g * HID + t]  = 0.0f;
}

// ==================== normalize + relu -> Hbp (+ pool on last layer) ====================
#define NORM_N 8
__global__ __launch_bounds__(HID) void k_norm(
    const float* __restrict__ H, const int* __restrict__ batch,
    const float* __restrict__ sc, const float* __restrict__ of,
    unsigned short* __restrict__ Hbp, float* __restrict__ pool, int accumulate) {
    int n0 = blockIdx.x * NORM_N;
    int t = threadIdx.x;
    int m = t & 15, tt = t >> 4;
    int g0 = batch[n0], gN = batch[n0 + NORM_N - 1];
    if (g0 == gN) {
        float ssc = sc[g0 * HID + t], sof = of[g0 * HID + t];
        float ps = 0.0f;
        #pragma unroll
        for (int i = 0; i < NORM_N; ++i) {
            float v = fmaxf(H[(size_t)(n0 + i) * HID + t] * ssc + sof, 0.0f);
            Hbp[(size_t)(n0 + i) * HID + m * 8 + tt] = f2bf(v);
            ps += v;
        }
        if (accumulate) atomicAdd(&pool[g0 * HID + t], ps);
    } else {
        #pragma unroll
        for (int i = 0; i < NORM_N; ++i) {
            int g = batch[n0 + i];
            float v = fmaxf(H[(size_t)(n0 + i) * HID + t] * sc[g * HID + t] + of[g * HID + t], 0.0f);
            Hbp[(size_t)(n0 + i) * HID + m * 8 + tt] = f2bf(v);
            if (accumulate) atomicAdd(&pool[g * HID + t], v);
        }
    }
}

// ==================== output head ====================
__global__ __launch_bounds__(HID) void k_head(
    const float* __restrict__ pool,
    const float* __restrict__ fw1, const float* __restrict__ fb1,
    const float* __restrict__ fw2, const float* __restrict__ fb2,
    float* __restrict__ out) {
    __shared__ float ps[HID];
    __shared__ float red[2];
    int g = blockIdx.x;
    int t = threadIdx.x;
    ps[t] = pool[g * HID + t];
    __syncthreads();
    float acc = fb1[t];
    #pragma unroll 4
    for (int k = 0; k < HID; ++k) acc = fmaf(ps[k], fw1[k * HID + t], acc);
    float p = fmaxf(acc, 0.0f) * fw2[t];
    #pragma unroll
    for (int off = 32; off > 0; off >>= 1) p += __shfl_down(p, off, 64);
    if ((t & 63) == 0) red[t >> 6] = p;
    __syncthreads();
    if (t == 0) out[g] = red[0] + red[1] + fb2[0];
}

extern "C" void kernel_launch(void* const* d_in, const int* in_sizes, int n_in,
                              void* d_out, int out_size, void* d_ws, size_t ws_size,
                              hipStream_t stream) {
    const float* x     = (const float*)d_in[0];
    const int*   ei    = (const int*)d_in[1];
    const float* ea    = (const float*)d_in[2];
    const int*   batch = (const int*)d_in[3];
    const float* lw1 = (const float*)d_in[4];
    const float* lb1 = (const float*)d_in[5];
    const float* lw2 = (const float*)d_in[6];
    const float* lb2 = (const float*)d_in[7];
    const float* pw1 = (const float*)d_in[8];
    const float* pb1 = (const float*)d_in[9];
    const float* pw2 = (const float*)d_in[10];
    const float* pb2 = (const float*)d_in[11];
    const float* ew  = (const float*)d_in[12];
    const float* eb  = (const float*)d_in[13];
    const float* nw1 = (const float*)d_in[14];
    const float* nb1 = (const float*)d_in[15];
    const float* nw2 = (const float*)d_in[16];
    const float* nb2 = (const float*)d_in[17];
    const float* gw  = (const float*)d_in[18];
    const float* gb  = (const float*)d_in[19];
    const float* gms = (const float*)d_in[20];
    const float* fw1 = (const float*)d_in[21];
    const float* fb1 = (const float*)d_in[22];
    const float* fw2 = (const float*)d_in[23];
    const float* fb2 = (const float*)d_in[24];
    float* out = (float*)d_out;

    float* ws   = (float*)d_ws;
    float* H    = ws;                          // 6,400,000 f
    float* A    = H    + (size_t)N_NODES * HID;// 6,400,000 f
    float* gsum = A    + (size_t)N_NODES * HID;
    float* gsq  = gsum + NGRAPH * HID;
    float* sc   = gsq  + NGRAPH * HID;
    float* of   = sc   + NGRAPH * HID;
    float* pool = of   + NGRAPH * HID;
    float* cnt  = pool + NGRAPH * HID;         // 128 f
    int* row_cnt   = (int*)(cnt + NGRAPH);     // 50000
    int* row_start = row_cnt + N_NODES;        // 50000
    int* row_fill  = row_start + N_NODES;      // 50000
    int* partial   = row_fill + N_NODES;       // 128
    int* csr_src   = partial + 128;            // 800000
    unsigned short* cea  = (unsigned short*)(csr_src + N_EDGES); // 12,800,000 bf16
    unsigned short* wt   = cea + (size_t)N_EDGES * EDGE_DIM;     // 98304
    unsigned short* wenc = wt + NLAYERS * 2 * HID * HID;         // 49152
    unsigned short* wte  = wenc + 49152;                         // 12288
    unsigned short* Hbp  = wte + NLAYERS * 8 * 64 * 8;           // 6,400,000 bf16 (12.8 MB)

    const int* srcs = ei;
    const int* dsts = ei + N_EDGES;

    // ---- init + CSR build + weight conversion ----
    k_init<<<(N_NODES + 255) / 256, 256, 0, stream>>>(row_cnt, pool, gsum, gsq);
    k_count<<<1, NGRAPH, 0, stream>>>(batch, cnt);
    k_wconv<<<(NLAYERS * 2 * HID * HID + 255) / 256, 256, 0, stream>>>(nw1, nw2, wt);
    k_wconv_enc<<<(49152 + 255) / 256, 256, 0, stream>>>(lw1, pw1, lw2, pw2, wenc);
    k_wconv_e<<<(NLAYERS * 8 * 64 * 8 + 255) / 256, 256, 0, stream>>>(ew, wte);
    k_hist<<<(N_EDGES + 255) / 256, 256, 0, stream>>>(dsts, row_cnt);
    k_scan1<<<NCHUNK, 256, 0, stream>>>(row_cnt, partial);
    k_scan2<<<1, 128, 0, stream>>>(partial);
    k_scan3<<<NCHUNK, 512, 0, stream>>>(row_cnt, partial, row_start, row_fill);
    k_fill<<<(N_EDGES + 255) / 256, 256, 0, stream>>>(srcs, dsts, ea, row_fill,
                                                      csr_src, cea);

    // ---- encoder (MFMA) -> Hbp ----
    k_encoder_mfma<<<(N_NODES + 63) / 64, 256, 0, stream>>>(
        x, wenc, lb1, lb2, pb1, pb2, Hbp);

    // ---- layers ----
    int mlp_blocks = (N_NODES + MLP_NODES_PER_BLOCK - 1) / MLP_NODES_PER_BLOCK;
    for (int l = 0; l < NLAYERS; ++l) {
        k_gather<<<N_NODES / 4, 256, 0, stream>>>(
            csr_src, cea, row_start, row_fill,
            wte + (size_t)l * 4096, eb + l * HID, Hbp, A);
        k_mlp_mfma<<<mlp_blocks, 256, 0, stream>>>(
            A, batch,
            wt + (size_t)l * 2 * HID * HID,
            wt + (size_t)l * 2 * HID * HID + HID * HID,
            nb1 + l * HID, nb2 + l * HID, H, gsum, gsq);
        k_stats<<<NGRAPH, HID, 0, stream>>>(gsum, gsq, cnt,
                                            gw + l * HID, gb + l * HID, gms + l * HID,
                                            sc, of);
        k_norm<<<N_NODES / NORM_N, HID, 0, stream>>>(
            H, batch, sc, of, Hbp, pool, (l == NLAYERS - 1) ? 1 : 0);
    }
    k_head<<<NGRAPH, HID, 0, stream>>>(pool, fw1, fb1, fw2, fb2, out);
}